// Round 5
// baseline (139.496 us; speedup 1.0000x reference)
//
#include <hip/hip_runtime.h>

#define S_LEN 2048
#define EMB_D 1024
#define QK_SCALE 0.08838834764831845f  // 1/sqrt(128)
#define RS128 11.313708498984761f      // sqrt(128)
#define LOG2E 1.4426950408889634f

typedef __bf16 bf16x8 __attribute__((ext_vector_type(8)));
typedef float f32x4 __attribute__((ext_vector_type(4)));
typedef unsigned short ushort_t;

typedef const __attribute__((address_space(1))) void gvoid;
typedef __attribute__((address_space(3))) void lvoid;

__device__ __forceinline__ unsigned short f2bf(float x) {
    unsigned u = __float_as_uint(x);
    unsigned r = u + 0x7FFFu + ((u >> 16) & 1u);  // RNE
    return (unsigned short)(r >> 16);
}

__device__ __forceinline__ void bfsplit(float x, unsigned short& hi, unsigned short& lo) {
    hi = f2bf(x);
    lo = f2bf(x - __uint_as_float((unsigned)hi << 16));
}

__device__ __forceinline__ void gl_lds(const void* g, void* l) {
    __builtin_amdgcn_global_load_lds((gvoid*)g, (lvoid*)l, 16, 0, 0);
}

// ---------------- kernel 1: build W bf16 B-frag blobs. Wf[ks_g][lane][8elem],
// ks_g = src*32 + hemb*4 + ks. n = lane&15 (out col: 0-7 ig, 8-15 fg), lg = lane>>4.
// W row e = src*1024 + hemb*128 + ks*32 + lg*8 + e_i. q-rows scaled by sqrt(128).
__global__ __launch_bounds__(256) void ktransW(const float* __restrict__ igk,
                                               const float* __restrict__ fgk,
                                               ushort_t* __restrict__ Wf) {
    int gid = blockIdx.x * 256 + threadIdx.x;  // 0..6143
    int ks_g = gid >> 6, lane = gid & 63;
    int n = lane & 15, lg = lane >> 4;
    int src = ks_g >> 5, rem = ks_g & 31;
    int hemb = rem >> 2, ks = rem & 3;
    int e0 = src * 1024 + hemb * 128 + ks * 32 + lg * 8;
    float scale = (src == 0) ? RS128 : 1.0f;
    const float* col = (n < 8) ? igk : fgk;
    int nn = n & 7;
    union { ushort_t u[8]; uint4 v4; } P;
    #pragma unroll
    for (int e = 0; e < 8; ++e) P.u[e] = f2bf(col[(size_t)(e0 + e) * 8 + nn] * scale);
    *(uint4*)((char*)Wf + ks_g * 1024 + lane * 16) = P.v4;
}

// ---------------- kernel 2: streaming split. Per block = (bh, tile64).
// Writes LINEAR Qh/Ql/Kh/Kl bf16 tiles [64r][128d], and swizzled transposed Vt.
__global__ __launch_bounds__(256) void ksplit(const float* __restrict__ q,
                                              const float* __restrict__ k,
                                              const float* __restrict__ v,
                                              ushort_t* __restrict__ QhG,
                                              ushort_t* __restrict__ QlG,
                                              ushort_t* __restrict__ KhG,
                                              ushort_t* __restrict__ KlG,
                                              ushort_t* __restrict__ VtG) {
    const int blk = blockIdx.x;
    const int bh = blk >> 5, tile = blk & 31;
    const int b = bh >> 3, hh = bh & 7;
    const int t = threadIdx.x;
    const size_t rowbase = (size_t)b * S_LEN + tile * 64;
    const float* qb = q + rowbase * EMB_D + hh * 128;
    const float* kb = k + rowbase * EMB_D + hh * 128;
    const float* vb = v + rowbase * EMB_D + hh * 128;
    const size_t tb = ((size_t)bh * 32 + tile) * 16384;
    char* Qh = (char*)QhG + tb;
    char* Ql = (char*)QlG + tb;
    char* Kh = (char*)KhG + tb;
    char* Kl = (char*)KlG + tb;
    char* Vt = (char*)VtG + tb;

    #pragma unroll
    for (int i = 0; i < 8; ++i) {
        int f = i * 256 + t;           // float4 idx 0..2047
        int r = f >> 5, c4 = f & 31;
        int off = r * 256 + c4 * 8;
        float4 fq = *(const float4*)(qb + (size_t)r * EMB_D + c4 * 4);
        ushort4 H, L;
        bfsplit(fq.x * QK_SCALE, H.x, L.x);
        bfsplit(fq.y * QK_SCALE, H.y, L.y);
        bfsplit(fq.z * QK_SCALE, H.z, L.z);
        bfsplit(fq.w * QK_SCALE, H.w, L.w);
        *(ushort4*)(Qh + off) = H;
        *(ushort4*)(Ql + off) = L;
        float4 fk = *(const float4*)(kb + (size_t)r * EMB_D + c4 * 4);
        bfsplit(fk.x, H.x, L.x);
        bfsplit(fk.y, H.y, L.y);
        bfsplit(fk.z, H.z, L.z);
        bfsplit(fk.w, H.w, L.w);
        *(ushort4*)(Kh + off) = H;
        *(ushort4*)(Kl + off) = L;
    }
    // V transpose: thread owns column d, 32 rows in registers. Coalesced row loads.
    const int d = t & 127, half2 = t >> 7;
    const int jb = half2 * 32;
    float col[32];
    #pragma unroll
    for (int j = 0; j < 32; ++j)
        col[j] = vb[(size_t)(jb + j) * EMB_D + d];
    const int swz = ((d & 7) ^ ((d >> 3) & 7)) << 4;
    #pragma unroll
    for (int g = 0; g < 4; ++g) {
        union { ushort_t u[8]; uint4 v4; } P;
        #pragma unroll
        for (int e = 0; e < 8; ++e) P.u[e] = f2bf(col[g * 8 + e]);
        *(uint4*)(Vt + ((d * 128 + (jb + g * 8) * 2) ^ swz)) = P.v4;
    }
}

// ---------------- kernel 3: gate GEMM via MFMA. 128 blocks = (b, tile, half32).
__global__ __launch_bounds__(256) void kgemm(const ushort_t* __restrict__ QhG,
                                             const ushort_t* __restrict__ KhG,
                                             const float* __restrict__ v,
                                             const ushort_t* __restrict__ Wf,
                                             const float* __restrict__ igb,
                                             const float* __restrict__ fgb,
                                             float* __restrict__ igp_t,
                                             float* __restrict__ fgp_t) {
    __shared__ __align__(16) ushort_t xs[4][2048];   // 4 KB per wave
    __shared__ __align__(16) float red[4][64][4];
    const int blk = blockIdx.x;
    const int b = blk >> 6, tile = (blk >> 1) & 31, half = blk & 1;
    const int t = threadIdx.x, w = t >> 6, lane = t & 63;
    const int m = w >> 1, kh = w & 1;
    const int ll = lane & 15, lg = lane >> 4;
    const int lrow = half * 32 + m * 16;   // tile-local strip row
    const int s0 = tile * 64 + lrow;       // seq row of strip
    f32x4 acc = {0.f, 0.f, 0.f, 0.f};
    char* myx = (char*)xs + w * 4096;

    for (int ri = kh * 12; ri < kh * 12 + 12; ++ri) {
        int src = ri >> 3, hemb = ri & 7;
        if (src < 2) {
            const char* tp = (const char*)(src ? KhG : QhG)
                           + ((size_t)(b * 8 + hemb) * 32 + tile) * 16384 + lrow * 256;
            #pragma unroll
            for (int i = 0; i < 4; ++i) {
                int a = i * 1024 + lane * 16;
                int sidx = a ^ (((a >> 8) & 7) << 4);
                gl_lds(tp + sidx, myx + i * 1024);
            }
            asm volatile("s_waitcnt vmcnt(0)" ::: "memory");
        } else {
            const float* vb = v + ((size_t)b * S_LEN + s0) * EMB_D + hemb * 128;
            #pragma unroll
            for (int i = 0; i < 8; ++i) {
                int f = i * 64 + lane;     // 512 float4 = 16 rows x 32
                int r = f >> 5, c4 = f & 31;
                float4 g = *(const float4*)(vb + (size_t)r * EMB_D + c4 * 4);
                ushort4 H;
                H.x = f2bf(g.x); H.y = f2bf(g.y); H.z = f2bf(g.z); H.w = f2bf(g.w);
                int off = (r * 256 + c4 * 8) ^ ((r & 7) << 4);
                *(ushort4*)(myx + off) = H;
            }
        }
        bf16x8 bf[4];
        #pragma unroll
        for (int ks = 0; ks < 4; ++ks)
            bf[ks] = *(const bf16x8*)((const char*)Wf + (src * 32 + hemb * 4 + ks) * 1024 + lane * 16);
        #pragma unroll
        for (int ks = 0; ks < 4; ++ks) {
            int aoff = (ll * 256 + lg * 16 + ks * 64) ^ ((ll & 7) << 4);
            bf16x8 af = *(const bf16x8*)(myx + aoff);
            acc = __builtin_amdgcn_mfma_f32_16x16x32_bf16(af, bf[ks], acc, 0, 0, 0);
        }
    }
    *(f32x4*)&red[w][lane][0] = acc;
    __syncthreads();
    if (kh == 0) {
        f32x4 o2 = acc + *(const f32x4*)&red[w + 1][lane][0];
        float bias = (ll < 8) ? igb[ll] : fgb[ll - 8];
        float* dst = (ll < 8) ? igp_t : fgp_t;
        size_t ob = (size_t)(b * 8 + (ll & 7)) * S_LEN + s0 + lg * 4;
        #pragma unroll
        for (int reg = 0; reg < 4; ++reg) dst[ob + reg] = o2[reg] + bias;
    }
}

// ---------------- kernel 4: per-(b,h) prefix scans, single wave, no barriers.
__global__ __launch_bounds__(64) void kscan(const float* __restrict__ igp_t,
                                            const float* __restrict__ fgp_t,
                                            float* __restrict__ a_w,
                                            float* __restrict__ pm_w,
                                            float* __restrict__ cs_w) {
    const int bh = blockIdx.x;
    const int l = threadIdx.x;
    const int base = bh * S_LEN + l * 32;
    float lf[32];
    #pragma unroll
    for (int i = 0; i < 8; ++i) {
        float4 fg = *(const float4*)(fgp_t + base + i * 4);
        float* p = &lf[i * 4];
        p[0] = fminf(fg.x, 0.f) - log1pf(__expf(-fabsf(fg.x)));
        p[1] = fminf(fg.y, 0.f) - log1pf(__expf(-fabsf(fg.y)));
        p[2] = fminf(fg.z, 0.f) - log1pf(__expf(-fabsf(fg.z)));
        p[3] = fminf(fg.w, 0.f) - log1pf(__expf(-fabsf(fg.w)));
    }
    #pragma unroll
    for (int i = 1; i < 32; ++i) lf[i] += lf[i - 1];
    float tot = lf[31];
    #pragma unroll
    for (int d = 1; d < 64; d <<= 1) {
        float n = __shfl_up(tot, d, 64);
        if (l >= d) tot += n;
    }
    float excl = tot - lf[31];
    float a[32];
    #pragma unroll
    for (int i = 0; i < 8; ++i) {
        float4 ig = *(const float4*)(igp_t + base + i * 4);
        float iv[4] = {ig.x, ig.y, ig.z, ig.w};
        #pragma unroll
        for (int e = 0; e < 4; ++e) {
            int idx = i * 4 + e;
            float cs = excl + lf[idx];
            cs_w[base + idx] = cs;
            a[idx] = iv[e] - cs;
            a_w[base + idx] = a[idx];
        }
    }
    float am[32];
    am[0] = a[0];
    #pragma unroll
    for (int i = 1; i < 32; ++i) am[i] = fmaxf(am[i - 1], a[i]);
    float mtot = am[31];
    #pragma unroll
    for (int d = 1; d < 64; d <<= 1) {
        float n = __shfl_up(mtot, d, 64);
        if (l >= d) mtot = fmaxf(mtot, n);
    }
    float exm = __shfl_up(mtot, 1, 64);
    if (l == 0) exm = -INFINITY;
    #pragma unroll
    for (int i = 0; i < 32; ++i) pm_w[base + i] = fmaxf(exm, am[i]);
}

// ---------------- kernel 5: main core. 512 blocks x 256 thr (4 waves, 2x2 grid).
// Complementary pairing: idx<256 -> rt=31-j, idx>=256 -> rt=j (round-robin gives
// each CU rt + (31-rt) = uniform 33 tile-steps). Phase-pipelined single-buffer
// staging: V[ct] issued before QK[ct]; K[ct+1] issued before PV[ct] -> every
// barrier's vmcnt(0) drain is covered by a full compute phase.
__global__ __launch_bounds__(256) void kmain(const ushort_t* __restrict__ QhG,
                                             const ushort_t* __restrict__ QlG,
                                             const ushort_t* __restrict__ KhG,
                                             const ushort_t* __restrict__ KlG,
                                             const ushort_t* __restrict__ VtG,
                                             const float* __restrict__ a_w,
                                             const float* __restrict__ pm_w,
                                             const float* __restrict__ cs_w,
                                             float* __restrict__ out) {
    __shared__ __align__(16) ushort_t KsH[8192];
    __shared__ __align__(16) ushort_t KsL[8192];
    __shared__ __align__(16) ushort_t Vs[8192];
    __shared__ __align__(16) ushort_t Cs[4096];
    __shared__ float red[2][64];

    const int idx = blockIdx.x;
    const int bh = idx & 15;              // bh&7 tracks XCD -> per-bh L2 affinity
    const int jj = (idx >> 4) & 15;
    const int rt = (idx < 256) ? (31 - jj) : jj;
    const int row0 = rt * 64;
    const int b = bh >> 3, h = bh & 7;
    const int t = threadIdx.x;
    const int w = t >> 6, lane = t & 63;
    const int wr = w >> 1, wc = w & 1;
    const int lg = lane >> 4, ll = lane & 15;

    const size_t bhoff = (size_t)bh * 524288;
    const char* qh_t = (const char*)QhG + bhoff + (size_t)rt * 16384;
    const char* ql_t = (const char*)QlG + bhoff + (size_t)rt * 16384;
    const char* kh_b = (const char*)KhG + bhoff;
    const char* kl_b = (const char*)KlG + bhoff;
    const char* vt_b = (const char*)VtG + bhoff;
    const float* aw = a_w + bh * S_LEN;

    // ---- prologue: stage Q hi/lo into K buffers (source-XOR)
    #pragma unroll
    for (int i = 0; i < 4; ++i) {
        int o = (w * 4 + i) * 1024;
        int a = o + lane * 16;
        int sidx = a ^ (((a >> 8) & 7) << 4);
        gl_lds(qh_t + sidx, (char*)KsH + o);
        gl_lds(ql_t + sidx, (char*)KsL + o);
    }
    __syncthreads();
    bf16x8 qfh[2][4], qfl[2][4];
    #pragma unroll
    for (int rf = 0; rf < 2; ++rf) {
        int rowA = 32 * wr + 16 * rf + ll;
        int sw = (rowA & 7) << 4;
        #pragma unroll
        for (int kk = 0; kk < 4; ++kk) {
            int off = (rowA * 256 + lg * 16 + kk * 64) ^ sw;
            qfh[rf][kk] = *(const bf16x8*)((const char*)KsH + off);
            qfl[rf][kk] = *(const bf16x8*)((const char*)KsL + off);
        }
    }
    float pm2[2][4];
    #pragma unroll
    for (int rf = 0; rf < 2; ++rf)
        #pragma unroll
        for (int r = 0; r < 4; ++r)
            pm2[rf][r] = pm_w[bh * S_LEN + row0 + 32 * wr + 16 * rf + 4 * lg + r] * LOG2E;
    __syncthreads();  // all waves done reading Q before K[0] overwrites

    // issue K[0]; prefetch a-coeffs for ct=0
    #pragma unroll
    for (int i = 0; i < 4; ++i) {
        int o = (w * 4 + i) * 1024;
        int a = o + lane * 16;
        int sidx = a ^ (((a >> 8) & 7) << 4);
        gl_lds(kh_b + sidx, (char*)KsH + o);
        gl_lds(kl_b + sidx, (char*)KsL + o);
    }
    float a0n = aw[32 * wc + ll] * LOG2E;
    float a1n = aw[32 * wc + 16 + ll] * LOG2E;

    f32x4 zero4 = {0.f, 0.f, 0.f, 0.f};
    f32x4 accO[2][4];
    #pragma unroll
    for (int rf = 0; rf < 2; ++rf)
        #pragma unroll
        for (int vf = 0; vf < 4; ++vf) accO[rf][vf] = zero4;
    float rs[2][4] = {{0.f, 0.f, 0.f, 0.f}, {0.f, 0.f, 0.f, 0.f}};

    for (int ct = 0; ct <= rt; ++ct) {
        __syncthreads();  // A: K[ct] landed; Vs/Cs free
        // B: issue V[ct] (pre-swizzled, linear copy)
        {
            const char* vt_t = vt_b + (size_t)ct * 16384;
            #pragma unroll
            for (int i = 0; i < 4; ++i) {
                int o = (w * 4 + i) * 1024;
                gl_lds(vt_t + o + lane * 16, (char*)Vs + o);
            }
        }
        float aj0 = a0n, aj1 = a1n;
        // C: QK^T (split precision)
        f32x4 accS[2][2];
        accS[0][0] = zero4; accS[0][1] = zero4; accS[1][0] = zero4; accS[1][1] = zero4;
        __builtin_amdgcn_s_setprio(1);
        #pragma unroll
        for (int kk = 0; kk < 4; ++kk) {
            #pragma unroll
            for (int cf = 0; cf < 2; ++cf) {
                int rowB = 32 * wc + 16 * cf + ll;
                int off = (rowB * 256 + lg * 16 + kk * 64) ^ ((rowB & 7) << 4);
                bf16x8 kh = *(const bf16x8*)((const char*)KsH + off);
                bf16x8 klo = *(const bf16x8*)((const char*)KsL + off);
                #pragma unroll
                for (int rf = 0; rf < 2; ++rf) {
                    accS[rf][cf] = __builtin_amdgcn_mfma_f32_16x16x32_bf16(qfh[rf][kk], kh, accS[rf][cf], 0, 0, 0);
                    accS[rf][cf] = __builtin_amdgcn_mfma_f32_16x16x32_bf16(qfl[rf][kk], kh, accS[rf][cf], 0, 0, 0);
                    accS[rf][cf] = __builtin_amdgcn_mfma_f32_16x16x32_bf16(qfh[rf][kk], klo, accS[rf][cf], 0, 0, 0);
                }
            }
        }
        __builtin_amdgcn_s_setprio(0);
        // epilogue: decay, mask, rowsum, Cs write
        const bool diag = (ct == rt);
        #pragma unroll
        for (int cf = 0; cf < 2; ++cf) {
            int jl = 32 * wc + 16 * cf + ll;
            float aj2 = cf ? aj1 : aj0;
            #pragma unroll
            for (int rf = 0; rf < 2; ++rf) {
                #pragma unroll
                for (int r = 0; r < 4; ++r) {
                    int il = 32 * wr + 16 * rf + 4 * lg + r;
                    float cval = accS[rf][cf][r] * exp2f(aj2 - pm2[rf][r]);
                    if (diag && jl > il) cval = 0.f;
                    rs[rf][r] += cval;
                    *(ushort_t*)((char*)Cs + ((il * 128 + jl * 2) ^ ((il & 7) << 4))) = f2bf(cval);
                }
            }
        }
        __syncthreads();  // D: V[ct] landed; Cs visible; K buffers free
        // E: issue K[ct+1]; prefetch a-coeffs
        if (ct < rt) {
            const char* kh_t = kh_b + (size_t)(ct + 1) * 16384;
            const char* kl_t = kl_b + (size_t)(ct + 1) * 16384;
            #pragma unroll
            for (int i = 0; i < 4; ++i) {
                int o = (w * 4 + i) * 1024;
                int a = o + lane * 16;
                int sidx = a ^ (((a >> 8) & 7) << 4);
                gl_lds(kh_t + sidx, (char*)KsH + o);
                gl_lds(kl_t + sidx, (char*)KsL + o);
            }
            a0n = aw[(ct + 1) * 64 + 32 * wc + ll] * LOG2E;
            a1n = aw[(ct + 1) * 64 + 32 * wc + 16 + ll] * LOG2E;
        }
        // F: PV
        __builtin_amdgcn_s_setprio(1);
        #pragma unroll
        for (int kk = 0; kk < 2; ++kk) {
            #pragma unroll
            for (int rf = 0; rf < 2; ++rf) {
                int rowA = 32 * wr + 16 * rf + ll;
                int offA = (rowA * 128 + lg * 16 + kk * 64) ^ ((rowA & 7) << 4);
                bf16x8 afr = *(const bf16x8*)((const char*)Cs + offA);
                #pragma unroll
                for (int vf = 0; vf < 4; ++vf) {
                    int rowB = 64 * wc + 16 * vf + ll;
                    int offB = rowB * 128 + ((lg * 16 + kk * 64) ^ (((rowB & 7) ^ ((rowB >> 3) & 7)) << 4));
                    bf16x8 bfr = *(const bf16x8*)((const char*)Vs + offB);
                    accO[rf][vf] = __builtin_amdgcn_mfma_f32_16x16x32_bf16(afr, bfr, accO[rf][vf], 0, 0, 0);
                }
            }
        }
        __builtin_amdgcn_s_setprio(0);
    }

    // ---- finalize
    #pragma unroll
    for (int m = 1; m < 16; m <<= 1)
        #pragma unroll
        for (int rf = 0; rf < 2; ++rf)
            #pragma unroll
            for (int r = 0; r < 4; ++r) rs[rf][r] += __shfl_xor(rs[rf][r], m);
    if (ll == 0) {
        #pragma unroll
        for (int rf = 0; rf < 2; ++rf)
            #pragma unroll
            for (int r = 0; r < 4; ++r)
                red[wc][32 * wr + 16 * rf + 4 * lg + r] = rs[rf][r];
    }
    __syncthreads();
    float invn[2][4], scl[2][4];
    #pragma unroll
    for (int rf = 0; rf < 2; ++rf) {
        #pragma unroll
        for (int r = 0; r < 4; ++r) {
            int il = 32 * wr + 16 * rf + 4 * lg + r;
            float tot2 = red[0][il] + red[1][il];
            float pmn = pm_w[bh * S_LEN + row0 + il];
            float csn = cs_w[bh * S_LEN + row0 + il];
            float nm = fmaxf(fabsf(tot2), __expf(-(csn + pmn))) + 1e-6f;
            invn[rf][r] = 1.0f / nm;
        }
    }
    float ss[2][4] = {{0.f, 0.f, 0.f, 0.f}, {0.f, 0.f, 0.f, 0.f}};
    #pragma unroll
    for (int rf = 0; rf < 2; ++rf)
        #pragma unroll
        for (int vf = 0; vf < 4; ++vf)
            #pragma unroll
            for (int r = 0; r < 4; ++r) {
                float hv = accO[rf][vf][r] * invn[rf][r];
                ss[rf][r] += hv * hv;
            }
    #pragma unroll
    for (int m = 1; m < 16; m <<= 1)
        #pragma unroll
        for (int rf = 0; rf < 2; ++rf)
            #pragma unroll
            for (int r = 0; r < 4; ++r) ss[rf][r] += __shfl_xor(ss[rf][r], m);
    __syncthreads();
    if (ll == 0) {
        #pragma unroll
        for (int rf = 0; rf < 2; ++rf)
            #pragma unroll
            for (int r = 0; r < 4; ++r)
                red[wc][32 * wr + 16 * rf + 4 * lg + r] = ss[rf][r];
    }
    __syncthreads();
    #pragma unroll
    for (int rf = 0; rf < 2; ++rf)
        #pragma unroll
        for (int r = 0; r < 4; ++r) {
            int il = 32 * wr + 16 * rf + 4 * lg + r;
            float sst = red[0][il] + red[1][il];
            scl[rf][r] = rsqrtf(sst * (1.0f / 128.0f) + 1e-6f) * invn[rf][r];
        }
    float* ob = out + ((size_t)b * S_LEN + row0) * EMB_D + h * 128;
    #pragma unroll
    for (int rf = 0; rf < 2; ++rf)
        #pragma unroll
        for (int r = 0; r < 4; ++r) {
            int il = 32 * wr + 16 * rf + 4 * lg + r;
            #pragma unroll
            for (int vf = 0; vf < 4; ++vf) {
                int d = 64 * wc + 16 * vf + ll;
                ob[(size_t)il * EMB_D + d] = accO[rf][vf][r] * scl[rf][r];
            }
        }
}

extern "C" void kernel_launch(void* const* d_in, const int* in_sizes, int n_in,
                              void* d_out, int out_size, void* d_ws, size_t ws_size,
                              hipStream_t stream) {
    const float* q   = (const float*)d_in[0];
    const float* k   = (const float*)d_in[1];
    const float* v   = (const float*)d_in[2];
    const float* igk = (const float*)d_in[3];
    const float* igb = (const float*)d_in[4];
    const float* fgk = (const float*)d_in[5];
    const float* fgb = (const float*)d_in[6];
    float* out = (float*)d_out;

    char* W = (char*)d_ws;
    ushort_t* Wf   = (ushort_t*)(W);                 //  98304 B
    float* igp_t   = (float*)(W + 98304);            // 131072 B
    float* fgp_t   = (float*)(W + 229376);
    float* a_w     = (float*)(W + 360448);
    float* pm_w    = (float*)(W + 491520);
    float* cs_w    = (float*)(W + 622592);
    ushort_t* QhG  = (ushort_t*)(W + 753664);        // 8 MB each
    ushort_t* QlG  = (ushort_t*)(W + 753664 + 1 * 8388608ull);
    ushort_t* KhG  = (ushort_t*)(W + 753664 + 2 * 8388608ull);
    ushort_t* KlG  = (ushort_t*)(W + 753664 + 3 * 8388608ull);
    ushort_t* VtG  = (ushort_t*)(W + 753664 + 4 * 8388608ull);  // total ~42.7 MB

    ktransW<<<24, 256, 0, stream>>>(igk, fgk, Wf);
    ksplit<<<512, 256, 0, stream>>>(q, k, v, QhG, QlG, KhG, KlG, VtG);
    kgemm<<<128, 256, 0, stream>>>(QhG, KhG, v, Wf, igb, fgb, igp_t, fgp_t);
    kscan<<<16, 64, 0, stream>>>(igp_t, fgp_t, a_w, pm_w, cs_w);
    kmain<<<512, 256, 0, stream>>>(QhG, QlG, KhG, KlG, VtG, a_w, pm_w, cs_w, out);
}

// Round 6
// 136.609 us; speedup vs baseline: 1.0211x; 1.0211x over previous
//
#include <hip/hip_runtime.h>

#define S_LEN 2048
#define EMB_D 1024
#define QK_SCALE 0.08838834764831845f  // 1/sqrt(128)
#define RS128 11.313708498984761f      // sqrt(128)
#define LOG2E 1.4426950408889634f

typedef _Float16 f16;
typedef f16 f16x8 __attribute__((ext_vector_type(8)));
typedef f16 f16x2 __attribute__((ext_vector_type(2)));
typedef float f32x4 __attribute__((ext_vector_type(4)));
typedef unsigned short ushort_t;

__device__ __forceinline__ ushort_t f2h(float x) {
    return __builtin_bit_cast(ushort_t, (f16)x);   // RNE
}
__device__ __forceinline__ unsigned pk2h(float a, float b) {
    return __builtin_bit_cast(unsigned, __builtin_amdgcn_cvt_pkrtz(a, b));
}

// ---------------- kernel 1: W fp16 B-frag blobs. Wf[ks_g][lane][8], ks_g = src*32+hemb*4+ks.
// lane: n = lane&15 (0-7 ig, 8-15 fg), lg = lane>>4. q-rows scaled by sqrt(128).
__global__ __launch_bounds__(256) void ktransW(const float* __restrict__ igk,
                                               const float* __restrict__ fgk,
                                               ushort_t* __restrict__ Wf) {
    int gid = blockIdx.x * 256 + threadIdx.x;  // 0..6143
    int ks_g = gid >> 6, lane = gid & 63;
    int n = lane & 15, lg = lane >> 4;
    int src = ks_g >> 5, rem = ks_g & 31;
    int hemb = rem >> 2, ks = rem & 3;
    int e0 = src * 1024 + hemb * 128 + ks * 32 + lg * 8;
    float scale = (src == 0) ? RS128 : 1.0f;
    const float* col = (n < 8) ? igk : fgk;
    int nn = n & 7;
    union { ushort_t u[8]; uint4 v4; } P;
    #pragma unroll
    for (int e = 0; e < 8; ++e) P.u[e] = f2h(col[(size_t)(e0 + e) * 8 + nn] * scale);
    *(uint4*)((char*)Wf + ks_g * 1024 + lane * 16) = P.v4;
}

// ---------------- kernel 2: streaming fp16 split. Block = (bh, tile64), bh in low bits
// so writes land in XCD bh&7's L2 (same XCD kmain reads from). Linear Qf/Kf [64r][128d],
// linear transposed Vt [128d][64j]. No LDS.
__global__ __launch_bounds__(256) void ksplit(const float* __restrict__ q,
                                              const float* __restrict__ k,
                                              const float* __restrict__ v,
                                              ushort_t* __restrict__ Qf,
                                              ushort_t* __restrict__ Kf,
                                              ushort_t* __restrict__ Vt) {
    const int blk = blockIdx.x;
    const int bh = blk & 15, tile = blk >> 4;
    const int b = bh >> 3, hh = bh & 7;
    const int t = threadIdx.x;
    const size_t rowbase = (size_t)b * S_LEN + tile * 64;
    const float* qb = q + rowbase * EMB_D + hh * 128;
    const float* kb = k + rowbase * EMB_D + hh * 128;
    const float* vb = v + rowbase * EMB_D + hh * 128;
    const size_t tb = ((size_t)bh * 32 + tile) * 16384;
    char* Qd = (char*)Qf + tb;
    char* Kd = (char*)Kf + tb;
    char* Vd = (char*)Vt + tb;

    #pragma unroll
    for (int i = 0; i < 8; ++i) {
        int f = i * 256 + t, r = f >> 5, c4 = f & 31;
        int off = r * 256 + c4 * 8;
        float4 fq = *(const float4*)(qb + (size_t)r * EMB_D + c4 * 4);
        ushort4 H;
        H.x = f2h(fq.x * QK_SCALE); H.y = f2h(fq.y * QK_SCALE);
        H.z = f2h(fq.z * QK_SCALE); H.w = f2h(fq.w * QK_SCALE);
        *(ushort4*)(Qd + off) = H;
        float4 fk = *(const float4*)(kb + (size_t)r * EMB_D + c4 * 4);
        H.x = f2h(fk.x); H.y = f2h(fk.y); H.z = f2h(fk.z); H.w = f2h(fk.w);
        *(ushort4*)(Kd + off) = H;
    }
    // V transpose: thread owns column d, 32 rows in registers (coalesced row loads).
    const int d = t & 127, hf = t >> 7;
    const int jb = hf * 32;
    float col[32];
    #pragma unroll
    for (int j = 0; j < 32; ++j) col[j] = vb[(size_t)(jb + j) * EMB_D + d];
    #pragma unroll
    for (int g = 0; g < 4; ++g) {
        union { ushort_t u[8]; uint4 v4; } P;
        #pragma unroll
        for (int e = 0; e < 8; ++e) P.u[e] = f2h(col[g * 8 + e]);
        *(uint4*)(Vd + d * 128 + (jb + g * 8) * 2) = P.v4;
    }
}

// ---------------- kernel 3: gate GEMM via fp16 MFMA, all operands direct from L2.
// 128 blocks = (b, tile, half32). Wave: M-strip m = w>>1, K-half kh = w&1.
__global__ __launch_bounds__(256) void kgemm(const ushort_t* __restrict__ Qf,
                                             const ushort_t* __restrict__ Kf,
                                             const float* __restrict__ v,
                                             const ushort_t* __restrict__ Wf,
                                             const float* __restrict__ igb,
                                             const float* __restrict__ fgb,
                                             float* __restrict__ igp_t,
                                             float* __restrict__ fgp_t) {
    __shared__ __align__(16) float red[4][64][4];
    const int blk = blockIdx.x;
    const int b = blk >> 6, tile = (blk >> 1) & 31, half = blk & 1;
    const int t = threadIdx.x, w = t >> 6, lane = t & 63;
    const int m = w >> 1, kh = w & 1;
    const int ll = lane & 15, lg = lane >> 4;
    const int lrow = half * 32 + m * 16;
    const int s0 = tile * 64 + lrow;
    f32x4 acc = {0.f, 0.f, 0.f, 0.f};

    for (int ri = kh * 12; ri < kh * 12 + 12; ++ri) {
        int src = ri >> 3, hemb = ri & 7;
        f16x8 af[4];
        if (src < 2) {
            const char* tp = (const char*)(src ? Kf : Qf)
                           + ((size_t)(b * 8 + hemb) * 32 + tile) * 16384 + (lrow + ll) * 256;
            #pragma unroll
            for (int ks = 0; ks < 4; ++ks)
                af[ks] = *(const f16x8*)(tp + lg * 16 + ks * 64);
        } else {
            const float* vr = v + ((size_t)b * S_LEN + s0 + ll) * EMB_D + hemb * 128 + lg * 8;
            #pragma unroll
            for (int ks = 0; ks < 4; ++ks) {
                f32x4 x0 = *(const f32x4*)(vr + ks * 32);
                f32x4 x1 = *(const f32x4*)(vr + ks * 32 + 4);
                union { unsigned u[4]; f16x8 h; } U;
                U.u[0] = pk2h(x0[0], x0[1]); U.u[1] = pk2h(x0[2], x0[3]);
                U.u[2] = pk2h(x1[0], x1[1]); U.u[3] = pk2h(x1[2], x1[3]);
                af[ks] = U.h;
            }
        }
        #pragma unroll
        for (int ks = 0; ks < 4; ++ks) {
            f16x8 bf = *(const f16x8*)((const char*)Wf + (src * 32 + hemb * 4 + ks) * 1024 + lane * 16);
            acc = __builtin_amdgcn_mfma_f32_16x16x32_f16(af[ks], bf, acc, 0, 0, 0);
        }
    }
    *(f32x4*)&red[w][lane][0] = acc;
    __syncthreads();
    if (kh == 0) {
        f32x4 o2 = acc + *(const f32x4*)&red[w + 1][lane][0];
        float bias = (ll < 8) ? igb[ll] : fgb[ll - 8];
        float* dst = (ll < 8) ? igp_t : fgp_t;
        size_t ob = (size_t)(b * 8 + (ll & 7)) * S_LEN + s0 + lg * 4;
        #pragma unroll
        for (int r = 0; r < 4; ++r) dst[ob + r] = o2[r] + bias;
    }
}

// ---------------- kernel 4: per-(b,h) prefix scans, single wave, no barriers.
// Outputs: a_w, pm_w pre-multiplied by LOG2E; nf_w = exp(-(cs+pm)) precomputed.
__global__ __launch_bounds__(64) void kscan(const float* __restrict__ igp_t,
                                            const float* __restrict__ fgp_t,
                                            float* __restrict__ a_w,
                                            float* __restrict__ pm_w,
                                            float* __restrict__ nf_w) {
    const int bh = blockIdx.x;
    const int l = threadIdx.x;
    const int base = bh * S_LEN + l * 32;
    float lf[32];
    #pragma unroll
    for (int i = 0; i < 8; ++i) {
        float4 fg = *(const float4*)(fgp_t + base + i * 4);
        float* p = &lf[i * 4];
        p[0] = fminf(fg.x, 0.f) - log1pf(__expf(-fabsf(fg.x)));
        p[1] = fminf(fg.y, 0.f) - log1pf(__expf(-fabsf(fg.y)));
        p[2] = fminf(fg.z, 0.f) - log1pf(__expf(-fabsf(fg.z)));
        p[3] = fminf(fg.w, 0.f) - log1pf(__expf(-fabsf(fg.w)));
    }
    #pragma unroll
    for (int i = 1; i < 32; ++i) lf[i] += lf[i - 1];
    float tot = lf[31];
    #pragma unroll
    for (int d = 1; d < 64; d <<= 1) {
        float n = __shfl_up(tot, d, 64);
        if (l >= d) tot += n;
    }
    float excl = tot - lf[31];
    float cs[32], a[32];
    #pragma unroll
    for (int i = 0; i < 8; ++i) {
        float4 ig = *(const float4*)(igp_t + base + i * 4);
        float iv[4] = {ig.x, ig.y, ig.z, ig.w};
        #pragma unroll
        for (int e = 0; e < 4; ++e) {
            int idx = i * 4 + e;
            cs[idx] = excl + lf[idx];
            a[idx] = iv[e] - cs[idx];
            a_w[base + idx] = a[idx] * LOG2E;
        }
    }
    float am[32];
    am[0] = a[0];
    #pragma unroll
    for (int i = 1; i < 32; ++i) am[i] = fmaxf(am[i - 1], a[i]);
    float mtot = am[31];
    #pragma unroll
    for (int d = 1; d < 64; d <<= 1) {
        float n = __shfl_up(mtot, d, 64);
        if (l >= d) mtot = fmaxf(mtot, n);
    }
    float exm = __shfl_up(mtot, 1, 64);
    if (l == 0) exm = -INFINITY;
    #pragma unroll
    for (int i = 0; i < 32; ++i) {
        float pmv = fmaxf(exm, am[i]);
        pm_w[base + i] = pmv * LOG2E;
        nf_w[base + i] = __expf(-(cs[i] + pmv));
    }
}

// ---------------- kernel 5: main core. 512 blocks x 256 thr (4 waves, 2x2 grid).
// All operands (Q,K,V,a) direct L2->reg with one-step register prefetch.
// Swapped QK^T (mfma(K,Q) -> S^T fragment layout) so Cs writes are 8B-wide.
// Only Cs goes through LDS (double-buffered); ONE LDS-only barrier per step
// (lgkmcnt(0)+s_barrier, vmem stays in flight).
__global__ __launch_bounds__(256) void kmain(const ushort_t* __restrict__ Qf,
                                             const ushort_t* __restrict__ Kf,
                                             const ushort_t* __restrict__ Vt,
                                             const float* __restrict__ a_w,
                                             const float* __restrict__ pm_w,
                                             const float* __restrict__ nf_w,
                                             float* __restrict__ out) {
    __shared__ __align__(16) ushort_t Cs[2][4096];   // 8KB x2, fp16 P tile
    __shared__ float red[2][2][64];

    const int idx = blockIdx.x;
    const int bh = idx & 15;              // XCD = idx%8 = bh&7 -> per-bh L2 affinity
    const int jj = (idx >> 4) & 15;
    const int rt = (idx < 256) ? (31 - jj) : jj;   // complementary pairing: CU gets 33 steps
    const int row0 = rt * 64;
    const int b = bh >> 3, h = bh & 7;
    const int t = threadIdx.x;
    const int w = t >> 6, lane = t & 63;
    const int wr = w >> 1, wc = w & 1;
    const int lg = lane >> 4, ll = lane & 15;

    const char* qt = (const char*)Qf + (size_t)bh * 524288 + (size_t)rt * 16384;
    const char* kb = (const char*)Kf + (size_t)bh * 524288;
    const char* vb = (const char*)Vt + (size_t)bh * 524288;
    const float* aw = a_w + bh * S_LEN;

    // Q frags (B operand: lane ll = Q row i), invariant over ct
    f16x8 qf[2][4];
    #pragma unroll
    for (int ib = 0; ib < 2; ++ib)
        #pragma unroll
        for (int kk = 0; kk < 4; ++kk)
            qf[ib][kk] = *(const f16x8*)(qt + (32 * wr + 16 * ib + ll) * 256 + lg * 16 + kk * 64);
    float pm2[2];
    #pragma unroll
    for (int ib = 0; ib < 2; ++ib)
        pm2[ib] = pm_w[bh * S_LEN + row0 + 32 * wr + 16 * ib + ll];  // pre-scaled by LOG2E

    // prefetch ct=0 operands into registers
    f16x8 kf[2][4];   // K[j = 32wc+16jb+ll][d chunks]
    #pragma unroll
    for (int jb = 0; jb < 2; ++jb)
        #pragma unroll
        for (int kk = 0; kk < 4; ++kk)
            kf[jb][kk] = *(const f16x8*)(kb + (32 * wc + 16 * jb + ll) * 256 + lg * 16 + kk * 64);
    f16x8 bv[2][4];   // V^T[d = 64wc+16vf+ll][j = kk*32+lg*8]
    #pragma unroll
    for (int kk = 0; kk < 2; ++kk)
        #pragma unroll
        for (int vf = 0; vf < 4; ++vf)
            bv[kk][vf] = *(const f16x8*)(vb + (64 * wc + 16 * vf + ll) * 128 + kk * 64 + lg * 16);
    f32x4 av[2];
    #pragma unroll
    for (int jb = 0; jb < 2; ++jb)
        av[jb] = *(const f32x4*)(aw + 32 * wc + 16 * jb + 4 * lg);

    f32x4 zero4 = {0.f, 0.f, 0.f, 0.f};
    f32x4 accO[2][4];
    #pragma unroll
    for (int ib = 0; ib < 2; ++ib)
        #pragma unroll
        for (int vf = 0; vf < 4; ++vf) accO[ib][vf] = zero4;
    float rs[2] = {0.f, 0.f};

    for (int ct = 0; ct <= rt; ++ct) {
        // QK^T (swapped): accST[jb][ib][r] = S[i=ll+16ib+32wr][j=4lg+r+16jb+32wc]
        f32x4 accST[2][2];
        accST[0][0] = zero4; accST[0][1] = zero4; accST[1][0] = zero4; accST[1][1] = zero4;
        __builtin_amdgcn_s_setprio(1);
        #pragma unroll
        for (int kk = 0; kk < 4; ++kk)
            #pragma unroll
            for (int jb = 0; jb < 2; ++jb)
                #pragma unroll
                for (int ib = 0; ib < 2; ++ib)
                    accST[jb][ib] = __builtin_amdgcn_mfma_f32_16x16x32_f16(
                        kf[jb][kk], qf[ib][kk], accST[jb][ib], 0, 0, 0);
        __builtin_amdgcn_s_setprio(0);
        // prefetch K[ct+1] (kf dead; latency covered until next step's QK)
        if (ct < rt) {
            const char* kt = kb + (size_t)(ct + 1) * 16384;
            #pragma unroll
            for (int jb = 0; jb < 2; ++jb)
                #pragma unroll
                for (int kk = 0; kk < 4; ++kk)
                    kf[jb][kk] = *(const f16x8*)(kt + (32 * wc + 16 * jb + ll) * 256 + lg * 16 + kk * 64);
        }
        // epilogue: decay, mask, rowsum, pack fp16, wide Cs write
        const bool diag = (ct == rt);
        ushort_t* cbuf = Cs[ct & 1];
        #pragma unroll
        for (int jb = 0; jb < 2; ++jb) {
            #pragma unroll
            for (int ib = 0; ib < 2; ++ib) {
                float cv[4];
                #pragma unroll
                for (int r = 0; r < 4; ++r) {
                    int jl = 32 * wc + 16 * jb + 4 * lg + r;
                    int il = 32 * wr + 16 * ib + ll;
                    float x = accST[jb][ib][r] * exp2f(av[jb][r] - pm2[ib]);
                    if (diag && jl > il) x = 0.f;
                    rs[ib] += x;
                    cv[r] = x;
                }
                int row = 32 * wr + 16 * ib + ll;
                int colb = (32 * wc + 16 * jb + 4 * lg) * 2;
                int off = (row * 128 + colb) ^ ((row & 7) << 4);
                uint2 pk2; pk2.x = pk2h(cv[0], cv[1]); pk2.y = pk2h(cv[2], cv[3]);
                *(uint2*)((char*)cbuf + off) = pk2;
            }
        }
        // LDS-only barrier: drain ds ops, leave vmem (prefetches) in flight
        asm volatile("s_waitcnt lgkmcnt(0)\n\ts_barrier" ::: "memory");
        // PV: O[i=4lg+r+16ib+32wr][d=ll+16vf+64wc] += P * V
        __builtin_amdgcn_s_setprio(1);
        #pragma unroll
        for (int kk = 0; kk < 2; ++kk)
            #pragma unroll
            for (int ib = 0; ib < 2; ++ib) {
                int rowA = 32 * wr + 16 * ib + ll;
                int offA = (rowA * 128 + lg * 16 + kk * 64) ^ ((rowA & 7) << 4);
                f16x8 pa = *(const f16x8*)((const char*)cbuf + offA);
                #pragma unroll
                for (int vf = 0; vf < 4; ++vf)
                    accO[ib][vf] = __builtin_amdgcn_mfma_f32_16x16x32_f16(
                        pa, bv[kk][vf], accO[ib][vf], 0, 0, 0);
            }
        __builtin_amdgcn_s_setprio(0);
        // prefetch V[ct+1], a[ct+1] (bv dead; covered by next QK+epilogue)
        if (ct < rt) {
            const char* vt = vb + (size_t)(ct + 1) * 16384;
            #pragma unroll
            for (int kk = 0; kk < 2; ++kk)
                #pragma unroll
                for (int vf = 0; vf < 4; ++vf)
                    bv[kk][vf] = *(const f16x8*)(vt + (64 * wc + 16 * vf + ll) * 128 + kk * 64 + lg * 16);
            const float* an = aw + (ct + 1) * 64;
            #pragma unroll
            for (int jb = 0; jb < 2; ++jb)
                av[jb] = *(const f32x4*)(an + 32 * wc + 16 * jb + 4 * lg);
        }
    }

    // ---- finalize: rowsum (reduce over lg), normalizer, RMSNorm (reduce over ll), store
    #pragma unroll
    for (int ib = 0; ib < 2; ++ib) {
        rs[ib] += __shfl_xor(rs[ib], 16);
        rs[ib] += __shfl_xor(rs[ib], 32);
    }
    if (lg == 0) {
        #pragma unroll
        for (int ib = 0; ib < 2; ++ib)
            red[0][wc][32 * wr + 16 * ib + ll] = rs[ib];
    }
    __syncthreads();
    float invn[2][4];
    #pragma unroll
    for (int ib = 0; ib < 2; ++ib)
        #pragma unroll
        for (int r = 0; r < 4; ++r) {
            int il = 32 * wr + 16 * ib + 4 * lg + r;
            float tot = red[0][0][il] + red[0][1][il];
            float nf = nf_w[bh * S_LEN + row0 + il];
            invn[ib][r] = 1.0f / (fmaxf(fabsf(tot), nf) + 1e-6f);
        }
    float ss[2][4] = {{0.f, 0.f, 0.f, 0.f}, {0.f, 0.f, 0.f, 0.f}};
    #pragma unroll
    for (int ib = 0; ib < 2; ++ib)
        #pragma unroll
        for (int vf = 0; vf < 4; ++vf)
            #pragma unroll
            for (int r = 0; r < 4; ++r) {
                float hv = accO[ib][vf][r] * invn[ib][r];
                ss[ib][r] += hv * hv;
            }
    #pragma unroll
    for (int m = 1; m < 16; m <<= 1)
        #pragma unroll
        for (int ib = 0; ib < 2; ++ib)
            #pragma unroll
            for (int r = 0; r < 4; ++r) ss[ib][r] += __shfl_xor(ss[ib][r], m);
    if (ll == 0) {
        #pragma unroll
        for (int ib = 0; ib < 2; ++ib)
            #pragma unroll
            for (int r = 0; r < 4; ++r)
                red[1][wc][32 * wr + 16 * ib + 4 * lg + r] = ss[ib][r];
    }
    __syncthreads();
    float* ob = out + ((size_t)b * S_LEN + row0) * EMB_D + h * 128;
    #pragma unroll
    for (int ib = 0; ib < 2; ++ib)
        #pragma unroll
        for (int r = 0; r < 4; ++r) {
            int il = 32 * wr + 16 * ib + 4 * lg + r;
            float sst = red[1][0][il] + red[1][1][il];
            float scl = rsqrtf(sst * (1.0f / 128.0f) + 1e-6f) * invn[ib][r];
            #pragma unroll
            for (int vf = 0; vf < 4; ++vf) {
                int d = 64 * wc + 16 * vf + ll;
                ob[(size_t)il * EMB_D + d] = accO[ib][vf][r] * scl;
            }
        }
}

extern "C" void kernel_launch(void* const* d_in, const int* in_sizes, int n_in,
                              void* d_out, int out_size, void* d_ws, size_t ws_size,
                              hipStream_t stream) {
    const float* q   = (const float*)d_in[0];
    const float* k   = (const float*)d_in[1];
    const float* v   = (const float*)d_in[2];
    const float* igk = (const float*)d_in[3];
    const float* igb = (const float*)d_in[4];
    const float* fgk = (const float*)d_in[5];
    const float* fgb = (const float*)d_in[6];
    float* out = (float*)d_out;

    char* W = (char*)d_ws;
    ushort_t* Wf   = (ushort_t*)(W);                 //  98304 B
    float* igp_t   = (float*)(W + 98304);            // 131072 B
    float* fgp_t   = (float*)(W + 229376);
    float* a_w     = (float*)(W + 360448);
    float* pm_w    = (float*)(W + 491520);
    float* nf_w    = (float*)(W + 622592);
    ushort_t* Qf   = (ushort_t*)(W + 753664);        // 8 MB each
    ushort_t* Kf   = (ushort_t*)(W + 753664 + 1 * 8388608ull);
    ushort_t* Vt   = (ushort_t*)(W + 753664 + 2 * 8388608ull);  // total ~25.9 MB

    ktransW<<<24, 256, 0, stream>>>(igk, fgk, Wf);
    ksplit<<<512, 256, 0, stream>>>(q, k, v, Qf, Kf, Vt);
    kgemm<<<128, 256, 0, stream>>>(Qf, Kf, v, Wf, igb, fgb, igp_t, fgp_t);
    kscan<<<16, 64, 0, stream>>>(igp_t, fgp_t, a_w, pm_w, nf_w);
    kmain<<<512, 256, 0, stream>>>(Qf, Kf, Vt, a_w, pm_w, nf_w, out);
}

// Round 7
// 92.670 us; speedup vs baseline: 1.5053x; 1.4741x over previous
//
#include <hip/hip_runtime.h>

#define S_LEN 2048
#define EMB_D 1024
#define QK_SCALE 0.08838834764831845f  // 1/sqrt(128)
#define RS128 11.313708498984761f      // sqrt(128)
#define LOG2E 1.4426950408889634f

typedef _Float16 f16;
typedef f16 f16x8 __attribute__((ext_vector_type(8)));
typedef float f32x4 __attribute__((ext_vector_type(4)));
typedef unsigned short ushort_t;

typedef const __attribute__((address_space(1))) void gvoid;
typedef __attribute__((address_space(3))) void lvoid;

__device__ __forceinline__ ushort_t f2h(float x) {
    return __builtin_bit_cast(ushort_t, (f16)x);   // RNE
}
__device__ __forceinline__ unsigned pk2h(float a, float b) {
    return __builtin_bit_cast(unsigned, __builtin_amdgcn_cvt_pkrtz(a, b));
}
__device__ __forceinline__ void gl_lds(const void* g, void* l) {
    __builtin_amdgcn_global_load_lds((gvoid*)g, (lvoid*)l, 16, 0, 0);
}

// ---------------- kernel 1: W fp16 B-frag blobs. Wf[ks_g][lane][8], ks_g = src*32+hemb*4+ks.
__global__ __launch_bounds__(256) void ktransW(const float* __restrict__ igk,
                                               const float* __restrict__ fgk,
                                               ushort_t* __restrict__ Wf) {
    int gid = blockIdx.x * 256 + threadIdx.x;  // 0..6143
    int ks_g = gid >> 6, lane = gid & 63;
    int n = lane & 15, lg = lane >> 4;
    int src = ks_g >> 5, rem = ks_g & 31;
    int hemb = rem >> 2, ks = rem & 3;
    int e0 = src * 1024 + hemb * 128 + ks * 32 + lg * 8;
    float scale = (src == 0) ? RS128 : 1.0f;
    const float* col = (n < 8) ? igk : fgk;
    int nn = n & 7;
    union { ushort_t u[8]; uint4 v4; } P;
    #pragma unroll
    for (int e = 0; e < 8; ++e) P.u[e] = f2h(col[(size_t)(e0 + e) * 8 + nn] * scale);
    *(uint4*)((char*)Wf + ks_g * 1024 + lane * 16) = P.v4;
}

// ---------------- kernel 2: streaming fp16 split. Block = (bh, tile64), bh in low bits
// (XCD affinity matches kmain). Writes PRE-SWIZZLED tiles: Q/K [64r][128d] with
// byte ^= ((r&7)<<4); Vt [128d][64j] with byte ^= ((d&7)<<4). No LDS.
__global__ __launch_bounds__(256) void ksplit(const float* __restrict__ q,
                                              const float* __restrict__ k,
                                              const float* __restrict__ v,
                                              ushort_t* __restrict__ Qf,
                                              ushort_t* __restrict__ Kf,
                                              ushort_t* __restrict__ Vt) {
    const int blk = blockIdx.x;
    const int bh = blk & 15, tile = blk >> 4;
    const int b = bh >> 3, hh = bh & 7;
    const int t = threadIdx.x;
    const size_t rowbase = (size_t)b * S_LEN + tile * 64;
    const float* qb = q + rowbase * EMB_D + hh * 128;
    const float* kb = k + rowbase * EMB_D + hh * 128;
    const float* vb = v + rowbase * EMB_D + hh * 128;
    const size_t tb = ((size_t)bh * 32 + tile) * 16384;
    char* Qd = (char*)Qf + tb;
    char* Kd = (char*)Kf + tb;
    char* Vd = (char*)Vt + tb;

    #pragma unroll
    for (int i = 0; i < 8; ++i) {
        int f = i * 256 + t, r = f >> 5, c4 = f & 31;
        int off = (r * 256 + c4 * 8) ^ ((r & 7) << 4);
        float4 fq = *(const float4*)(qb + (size_t)r * EMB_D + c4 * 4);
        ushort4 H;
        H.x = f2h(fq.x * QK_SCALE); H.y = f2h(fq.y * QK_SCALE);
        H.z = f2h(fq.z * QK_SCALE); H.w = f2h(fq.w * QK_SCALE);
        *(ushort4*)(Qd + off) = H;
        float4 fk = *(const float4*)(kb + (size_t)r * EMB_D + c4 * 4);
        H.x = f2h(fk.x); H.y = f2h(fk.y); H.z = f2h(fk.z); H.w = f2h(fk.w);
        *(ushort4*)(Kd + off) = H;
    }
    // V transpose: thread owns column d, 32 rows in registers (coalesced row loads).
    const int d = t & 127, hf = t >> 7;
    const int jb = hf * 32;
    float col[32];
    #pragma unroll
    for (int j = 0; j < 32; ++j) col[j] = vb[(size_t)(jb + j) * EMB_D + d];
    #pragma unroll
    for (int g = 0; g < 4; ++g) {
        union { ushort_t u[8]; uint4 v4; } P;
        #pragma unroll
        for (int e = 0; e < 8; ++e) P.u[e] = f2h(col[g * 8 + e]);
        *(uint4*)(Vd + ((d * 128 + (jb + g * 8) * 2) ^ ((d & 7) << 4))) = P.v4;
    }
}

// ---------------- kernel 3: gate GEMM via fp16 MFMA, operands direct from L2.
__global__ __launch_bounds__(256) void kgemm(const ushort_t* __restrict__ Qf,
                                             const ushort_t* __restrict__ Kf,
                                             const float* __restrict__ v,
                                             const ushort_t* __restrict__ Wf,
                                             const float* __restrict__ igb,
                                             const float* __restrict__ fgb,
                                             float* __restrict__ igp_t,
                                             float* __restrict__ fgp_t) {
    __shared__ __align__(16) float red[4][64][4];
    const int blk = blockIdx.x;
    const int b = blk >> 6, tile = (blk >> 1) & 31, half = blk & 1;
    const int t = threadIdx.x, w = t >> 6, lane = t & 63;
    const int m = w >> 1, kh = w & 1;
    const int ll = lane & 15, lg = lane >> 4;
    const int lrow = half * 32 + m * 16;
    const int s0 = tile * 64 + lrow;
    f32x4 acc = {0.f, 0.f, 0.f, 0.f};

    for (int ri = kh * 12; ri < kh * 12 + 12; ++ri) {
        int src = ri >> 3, hemb = ri & 7;
        f16x8 af[4];
        if (src < 2) {
            const char* tp = (const char*)(src ? Kf : Qf)
                           + ((size_t)(b * 8 + hemb) * 32 + tile) * 16384;
            int rowb = (lrow + ll) * 256;
            #pragma unroll
            for (int ks = 0; ks < 4; ++ks)
                af[ks] = *(const f16x8*)(tp + ((rowb + lg * 16 + ks * 64) ^ ((ll & 7) << 4)));
        } else {
            const float* vr = v + ((size_t)b * S_LEN + s0 + ll) * EMB_D + hemb * 128 + lg * 8;
            #pragma unroll
            for (int ks = 0; ks < 4; ++ks) {
                f32x4 x0 = *(const f32x4*)(vr + ks * 32);
                f32x4 x1 = *(const f32x4*)(vr + ks * 32 + 4);
                union { unsigned u[4]; f16x8 h; } U;
                U.u[0] = pk2h(x0[0], x0[1]); U.u[1] = pk2h(x0[2], x0[3]);
                U.u[2] = pk2h(x1[0], x1[1]); U.u[3] = pk2h(x1[2], x1[3]);
                af[ks] = U.h;
            }
        }
        #pragma unroll
        for (int ks = 0; ks < 4; ++ks) {
            f16x8 bf = *(const f16x8*)((const char*)Wf + (src * 32 + hemb * 4 + ks) * 1024 + lane * 16);
            acc = __builtin_amdgcn_mfma_f32_16x16x32_f16(af[ks], bf, acc, 0, 0, 0);
        }
    }
    *(f32x4*)&red[w][lane][0] = acc;
    __syncthreads();
    if (kh == 0) {
        f32x4 o2 = acc + *(const f32x4*)&red[w + 1][lane][0];
        float bias = (ll < 8) ? igb[ll] : fgb[ll - 8];
        float* dst = (ll < 8) ? igp_t : fgp_t;
        size_t ob = (size_t)(b * 8 + (ll & 7)) * S_LEN + s0 + lg * 4;
        #pragma unroll
        for (int r = 0; r < 4; ++r) dst[ob + r] = o2[r] + bias;
    }
}

// ---------------- kernel 4: per-(b,h) prefix scans, single wave, no barriers.
__global__ __launch_bounds__(64) void kscan(const float* __restrict__ igp_t,
                                            const float* __restrict__ fgp_t,
                                            float* __restrict__ a_w,
                                            float* __restrict__ pm_w,
                                            float* __restrict__ nf_w) {
    const int bh = blockIdx.x;
    const int l = threadIdx.x;
    const int base = bh * S_LEN + l * 32;
    float lf[32];
    #pragma unroll
    for (int i = 0; i < 8; ++i) {
        float4 fg = *(const float4*)(fgp_t + base + i * 4);
        float* p = &lf[i * 4];
        p[0] = fminf(fg.x, 0.f) - log1pf(__expf(-fabsf(fg.x)));
        p[1] = fminf(fg.y, 0.f) - log1pf(__expf(-fabsf(fg.y)));
        p[2] = fminf(fg.z, 0.f) - log1pf(__expf(-fabsf(fg.z)));
        p[3] = fminf(fg.w, 0.f) - log1pf(__expf(-fabsf(fg.w)));
    }
    #pragma unroll
    for (int i = 1; i < 32; ++i) lf[i] += lf[i - 1];
    float tot = lf[31];
    #pragma unroll
    for (int d = 1; d < 64; d <<= 1) {
        float n = __shfl_up(tot, d, 64);
        if (l >= d) tot += n;
    }
    float excl = tot - lf[31];
    float cs[32], a[32];
    #pragma unroll
    for (int i = 0; i < 8; ++i) {
        float4 ig = *(const float4*)(igp_t + base + i * 4);
        float iv[4] = {ig.x, ig.y, ig.z, ig.w};
        #pragma unroll
        for (int e = 0; e < 4; ++e) {
            int idx = i * 4 + e;
            cs[idx] = excl + lf[idx];
            a[idx] = iv[e] - cs[idx];
            a_w[base + idx] = a[idx] * LOG2E;
        }
    }
    float am[32];
    am[0] = a[0];
    #pragma unroll
    for (int i = 1; i < 32; ++i) am[i] = fmaxf(am[i - 1], a[i]);
    float mtot = am[31];
    #pragma unroll
    for (int d = 1; d < 64; d <<= 1) {
        float n = __shfl_up(mtot, d, 64);
        if (l >= d) mtot = fmaxf(mtot, n);
    }
    float exm = __shfl_up(mtot, 1, 64);
    if (l == 0) exm = -INFINITY;
    #pragma unroll
    for (int i = 0; i < 32; ++i) {
        float pmv = fmaxf(exm, am[i]);
        pm_w[base + i] = pmv * LOG2E;
        nf_w[base + i] = __expf(-(cs[i] + pmv));
    }
}

// ---------------- kernel 5: main core. 256 blocks x 512 thr (8 waves = 2 groups of 4).
// Block = (bh, pair): rt = pair then 31-pair (uniform 17 supersteps/block).
// Group g handles ct = g, g+2, ... (parity split); per-group 2x2 wave grid over
// 64x64 S-tile. K/V double-buffered in LDS via global_load_lds from pre-swizzled
// tiles; stage(ct+2) issued before compute(ct); vmcnt(0) only at superstep end.
// Mid-step barrier is lgkmcnt-only. Partial accO combined across groups via LDS.
__global__ __launch_bounds__(512) void kmain(const ushort_t* __restrict__ Qf,
                                             const ushort_t* __restrict__ Kf,
                                             const ushort_t* __restrict__ Vt,
                                             const float* __restrict__ a_w,
                                             const float* __restrict__ pm_w,
                                             const float* __restrict__ nf_w,
                                             float* __restrict__ out) {
    __shared__ __align__(16) ushort_t Kbuf[2][2][8192];  // [group][dbuf] 64KB
    __shared__ __align__(16) ushort_t Vbuf[2][2][8192];  // 64KB
    __shared__ __align__(16) ushort_t Csh[2][4096];      // [group] 16KB
    __shared__ float redL[2][2][64];                     // [phase][wc][row]

    const int blk = blockIdx.x;
    const int bh = blk & 15;             // XCD = blk%8 = bh&7
    const int pair = blk >> 4;           // 0..15
    const int b = bh >> 3, h = bh & 7;
    const int t = threadIdx.x;
    const int w = t >> 6, lane = t & 63;
    const int g = w >> 2, wl = w & 3;
    const int wr = wl >> 1, wc = wl & 1;
    const int lg = lane >> 4, ll = lane & 15;
    const int sw = (ll & 7) << 4;

    const char* q_b = (const char*)Qf + (size_t)bh * 524288;
    const char* k_b = (const char*)Kf + (size_t)bh * 524288;
    const char* v_b = (const char*)Vt + (size_t)bh * 524288;
    const float* aw = a_w + bh * S_LEN;

    float* accX = (float*)&Vbuf[1][0][0];   // 32KB combine region (aliased, post-loop)
    float* rsX  = (float*)&Csh[1][0];       // 2KB

    for (int half = 0; half < 2; ++half) {
        const int rt = half ? (31 - pair) : pair;
        const int row0 = rt * 64;
        const int nss = (rt >> 1) + 1;
        __syncthreads();   // LDS free from previous half

        // ---- prologue: stage Q (group0) into Kbuf[0][0]
        if (g == 0) {
            const char* qt = q_b + (size_t)rt * 16384;
            #pragma unroll
            for (int i = 0; i < 4; ++i) {
                int o = (wl * 4 + i) * 1024 + lane * 16;
                gl_lds(qt + o, (char*)&Kbuf[0][0][0] + o);
            }
        }
        asm volatile("s_waitcnt vmcnt(0)" ::: "memory");
        __builtin_amdgcn_s_barrier();
        // Q frags (both groups read the same tile) + pm
        f16x8 qf[2][4];
        #pragma unroll
        for (int ib = 0; ib < 2; ++ib) {
            int rowb = (32 * wr + 16 * ib + ll) * 256;
            #pragma unroll
            for (int kk = 0; kk < 4; ++kk)
                qf[ib][kk] = *(const f16x8*)((const char*)&Kbuf[0][0][0]
                                             + ((rowb + lg * 16 + kk * 64) ^ sw));
        }
        float pm2[2];
        #pragma unroll
        for (int ib = 0; ib < 2; ++ib)
            pm2[ib] = pm_w[bh * S_LEN + row0 + 32 * wr + 16 * ib + ll];
        asm volatile("s_waitcnt lgkmcnt(0)" ::: "memory");
        __builtin_amdgcn_s_barrier();   // Q reads done; Kbuf[0][0] free

        // stage K(ct=g), V(ct=g) into buf0
        if (g <= rt) {
            const char* kt = k_b + (size_t)g * 16384;
            const char* vt = v_b + (size_t)g * 16384;
            #pragma unroll
            for (int i = 0; i < 4; ++i) {
                int o = (wl * 4 + i) * 1024 + lane * 16;
                gl_lds(kt + o, (char*)&Kbuf[g][0][0] + o);
                gl_lds(vt + o, (char*)&Vbuf[g][0][0] + o);
            }
        }
        f32x4 avA[2] = {{0.f,0.f,0.f,0.f},{0.f,0.f,0.f,0.f}}, avB[2] = {{0.f,0.f,0.f,0.f},{0.f,0.f,0.f,0.f}};
        if (g <= rt) {
            #pragma unroll
            for (int jb = 0; jb < 2; ++jb)
                avA[jb] = *(const f32x4*)(aw + g * 64 + 32 * wc + 16 * jb + 4 * lg);
        }
        asm volatile("s_waitcnt vmcnt(0)" ::: "memory");
        __builtin_amdgcn_s_barrier();

        f32x4 zero4 = {0.f, 0.f, 0.f, 0.f};
        f32x4 accO[2][4];
        #pragma unroll
        for (int ib = 0; ib < 2; ++ib)
            #pragma unroll
            for (int vf = 0; vf < 4; ++vf) accO[ib][vf] = zero4;
        float rs[2] = {0.f, 0.f};

        for (int ss = 0; ss < nss; ++ss) {
            const int p = ss & 1;
            const int myct = 2 * ss + g;
            const int nxct = myct + 2;
            // issue next-tile staging into buf p^1 (drains at END of this superstep)
            if (nxct <= rt) {
                const char* kt = k_b + (size_t)nxct * 16384;
                const char* vt = v_b + (size_t)nxct * 16384;
                #pragma unroll
                for (int i = 0; i < 4; ++i) {
                    int o = (wl * 4 + i) * 1024 + lane * 16;
                    gl_lds(kt + o, (char*)&Kbuf[g][p ^ 1][0] + o);
                    gl_lds(vt + o, (char*)&Vbuf[g][p ^ 1][0] + o);
                }
                if (p == 0) {
                    #pragma unroll
                    for (int jb = 0; jb < 2; ++jb)
                        avB[jb] = *(const f32x4*)(aw + nxct * 64 + 32 * wc + 16 * jb + 4 * lg);
                } else {
                    #pragma unroll
                    for (int jb = 0; jb < 2; ++jb)
                        avA[jb] = *(const f32x4*)(aw + nxct * 64 + 32 * wc + 16 * jb + 4 * lg);
                }
            }
            const bool act = (myct <= rt);
            if (act) {
                const char* kl = (const char*)&Kbuf[g][p][0];
                f32x4 accST[2][2];
                accST[0][0] = zero4; accST[0][1] = zero4;
                accST[1][0] = zero4; accST[1][1] = zero4;
                __builtin_amdgcn_s_setprio(1);
                #pragma unroll
                for (int kk = 0; kk < 4; ++kk) {
                    f16x8 kf0 = *(const f16x8*)(kl + (((32 * wc + ll) * 256 + lg * 16 + kk * 64) ^ sw));
                    f16x8 kf1 = *(const f16x8*)(kl + (((32 * wc + 16 + ll) * 256 + lg * 16 + kk * 64) ^ sw));
                    accST[0][0] = __builtin_amdgcn_mfma_f32_16x16x32_f16(kf0, qf[0][kk], accST[0][0], 0, 0, 0);
                    accST[0][1] = __builtin_amdgcn_mfma_f32_16x16x32_f16(kf0, qf[1][kk], accST[0][1], 0, 0, 0);
                    accST[1][0] = __builtin_amdgcn_mfma_f32_16x16x32_f16(kf1, qf[0][kk], accST[1][0], 0, 0, 0);
                    accST[1][1] = __builtin_amdgcn_mfma_f32_16x16x32_f16(kf1, qf[1][kk], accST[1][1], 0, 0, 0);
                }
                __builtin_amdgcn_s_setprio(0);
                // epilogue: decay, mask, rowsum, pack fp16, Cs write
                const bool diag = (myct == rt);
                #pragma unroll
                for (int jb = 0; jb < 2; ++jb) {
                    f32x4 av = (p == 0) ? avA[jb] : avB[jb];
                    #pragma unroll
                    for (int ib = 0; ib < 2; ++ib) {
                        int il = 32 * wr + 16 * ib + ll;
                        float cv[4];
                        #pragma unroll
                        for (int r = 0; r < 4; ++r) {
                            int jl = 32 * wc + 16 * jb + 4 * lg + r;
                            float x = accST[jb][ib][r] * exp2f(av[r] - pm2[ib]);
                            if (diag && jl > il) x = 0.f;
                            rs[ib] += x;
                            cv[r] = x;
                        }
                        int off = (il * 128 + (32 * wc + 16 * jb + 4 * lg) * 2) ^ ((il & 7) << 4);
                        uint2 pk2; pk2.x = pk2h(cv[0], cv[1]); pk2.y = pk2h(cv[2], cv[3]);
                        *(uint2*)((char*)&Csh[g][0] + off) = pk2;
                    }
                }
            }
            // LDS-only barrier (vmem prefetches stay in flight)
            asm volatile("s_waitcnt lgkmcnt(0)" ::: "memory");
            __builtin_amdgcn_s_barrier();
            if (act) {
                const char* vl = (const char*)&Vbuf[g][p][0];
                __builtin_amdgcn_s_setprio(1);
                #pragma unroll
                for (int kk = 0; kk < 2; ++kk)
                    #pragma unroll
                    for (int ib = 0; ib < 2; ++ib) {
                        int rowA = 32 * wr + 16 * ib + ll;
                        f16x8 pa = *(const f16x8*)((const char*)&Csh[g][0]
                                                   + ((rowA * 128 + lg * 16 + kk * 64) ^ ((rowA & 7) << 4)));
                        #pragma unroll
                        for (int vf = 0; vf < 4; ++vf) {
                            int d = 64 * wc + 16 * vf + ll;
                            f16x8 vb2 = *(const f16x8*)(vl + ((d * 128 + kk * 64 + lg * 16) ^ sw));
                            accO[ib][vf] = __builtin_amdgcn_mfma_f32_16x16x32_f16(pa, vb2, accO[ib][vf], 0, 0, 0);
                        }
                    }
                __builtin_amdgcn_s_setprio(0);
            }
            // drain next-tile staging (flew the whole superstep), swap buffers
            asm volatile("s_waitcnt vmcnt(0)" ::: "memory");
            __builtin_amdgcn_s_barrier();
        }

        // ---- combine the two groups' partials, then finalize (group0)
        __syncthreads();
        const int li = wl * 64 + lane;
        if (g == 1) {
            #pragma unroll
            for (int ib = 0; ib < 2; ++ib)
                #pragma unroll
                for (int vf = 0; vf < 4; ++vf)
                    *(f32x4*)&accX[li * 32 + (ib * 4 + vf) * 4] = accO[ib][vf];
            rsX[li * 2 + 0] = rs[0];
            rsX[li * 2 + 1] = rs[1];
        }
        __syncthreads();
        if (g == 0) {
            #pragma unroll
            for (int ib = 0; ib < 2; ++ib)
                #pragma unroll
                for (int vf = 0; vf < 4; ++vf)
                    accO[ib][vf] += *(const f32x4*)&accX[li * 32 + (ib * 4 + vf) * 4];
            rs[0] += rsX[li * 2 + 0];
            rs[1] += rsX[li * 2 + 1];
            #pragma unroll
            for (int ib = 0; ib < 2; ++ib) {
                rs[ib] += __shfl_xor(rs[ib], 16);
                rs[ib] += __shfl_xor(rs[ib], 32);
            }
            if (lg == 0) {
                redL[0][wc][32 * wr + ll] = rs[0];
                redL[0][wc][32 * wr + 16 + ll] = rs[1];
            }
        }
        __syncthreads();
        if (g == 0) {
            float invn[2][4];
            #pragma unroll
            for (int ib = 0; ib < 2; ++ib)
                #pragma unroll
                for (int r = 0; r < 4; ++r) {
                    int il = 32 * wr + 16 * ib + 4 * lg + r;
                    float tot = redL[0][0][il] + redL[0][1][il];
                    float nf = nf_w[bh * S_LEN + row0 + il];
                    invn[ib][r] = 1.0f / (fmaxf(fabsf(tot), nf) + 1e-6f);
                }
            float ssq[2][4] = {{0.f, 0.f, 0.f, 0.f}, {0.f, 0.f, 0.f, 0.f}};
            #pragma unroll
            for (int ib = 0; ib < 2; ++ib)
                #pragma unroll
                for (int vf = 0; vf < 4; ++vf)
                    #pragma unroll
                    for (int r = 0; r < 4; ++r) {
                        float hv = accO[ib][vf][r] * invn[ib][r];
                        ssq[ib][r] += hv * hv;
                    }
            #pragma unroll
            for (int m = 1; m < 16; m <<= 1)
                #pragma unroll
                for (int ib = 0; ib < 2; ++ib)
                    #pragma unroll
                    for (int r = 0; r < 4; ++r) ssq[ib][r] += __shfl_xor(ssq[ib][r], m);
            if (ll == 0) {
                #pragma unroll
                for (int ib = 0; ib < 2; ++ib)
                    #pragma unroll
                    for (int r = 0; r < 4; ++r)
                        redL[1][wc][32 * wr + 16 * ib + 4 * lg + r] = ssq[ib][r];
            }
            __builtin_amdgcn_s_barrier();   // group-local enough: only g0 reads/writes redL[1]
            float* ob = out + ((size_t)b * S_LEN + row0) * EMB_D + h * 128;
            #pragma unroll
            for (int ib = 0; ib < 2; ++ib)
                #pragma unroll
                for (int r = 0; r < 4; ++r) {
                    int il = 32 * wr + 16 * ib + 4 * lg + r;
                    float sst = redL[1][0][il] + redL[1][1][il];
                    float scl = rsqrtf(sst * (1.0f / 128.0f) + 1e-6f) * invn[ib][r];
                    #pragma unroll
                    for (int vf = 0; vf < 4; ++vf) {
                        int d = 64 * wc + 16 * vf + ll;
                        ob[(size_t)il * EMB_D + d] = accO[ib][vf][r] * scl;
                    }
                }
        } else {
            __builtin_amdgcn_s_barrier();   // match g0's barrier
        }
    }
}

extern "C" void kernel_launch(void* const* d_in, const int* in_sizes, int n_in,
                              void* d_out, int out_size, void* d_ws, size_t ws_size,
                              hipStream_t stream) {
    const float* q   = (const float*)d_in[0];
    const float* k   = (const float*)d_in[1];
    const float* v   = (const float*)d_in[2];
    const float* igk = (const float*)d_in[3];
    const float* igb = (const float*)d_in[4];
    const float* fgk = (const float*)d_in[5];
    const float* fgb = (const float*)d_in[6];
    float* out = (float*)d_out;

    char* W = (char*)d_ws;
    ushort_t* Wf   = (ushort_t*)(W);                 //  98304 B
    float* igp_t   = (float*)(W + 98304);            // 131072 B
    float* fgp_t   = (float*)(W + 229376);
    float* a_w     = (float*)(W + 360448);
    float* pm_w    = (float*)(W + 491520);
    float* nf_w    = (float*)(W + 622592);
    ushort_t* Qf   = (ushort_t*)(W + 753664);        // 8 MB each
    ushort_t* Kf   = (ushort_t*)(W + 753664 + 1 * 8388608ull);
    ushort_t* Vt   = (ushort_t*)(W + 753664 + 2 * 8388608ull);  // total ~25.9 MB

    ktransW<<<24, 256, 0, stream>>>(igk, fgk, Wf);
    ksplit<<<512, 256, 0, stream>>>(q, k, v, Qf, Kf, Vt);
    kgemm<<<128, 256, 0, stream>>>(Qf, Kf, v, Wf, igb, fgb, igp_t, fgp_t);
    kscan<<<16, 64, 0, stream>>>(igp_t, fgp_t, a_w, pm_w, nf_w);
    kmain<<<256, 512, 0, stream>>>(Qf, Kf, Vt, a_w, pm_w, nf_w, out);
}

// Round 8
// 89.671 us; speedup vs baseline: 1.5556x; 1.0334x over previous
//
#include <hip/hip_runtime.h>

#define S_LEN 2048
#define EMB_D 1024
#define QK_SCALE 0.08838834764831845f  // 1/sqrt(128)
#define RS128 11.313708498984761f      // sqrt(128)
#define LOG2E 1.4426950408889634f

typedef _Float16 f16;
typedef f16 f16x8 __attribute__((ext_vector_type(8)));
typedef float f32x4 __attribute__((ext_vector_type(4)));
typedef unsigned short ushort_t;

typedef const __attribute__((address_space(1))) void gvoid;
typedef __attribute__((address_space(3))) void lvoid;

__device__ __forceinline__ ushort_t f2h(float x) {
    return __builtin_bit_cast(ushort_t, (f16)x);   // RNE
}
__device__ __forceinline__ unsigned pk2h(float a, float b) {
    return __builtin_bit_cast(unsigned, __builtin_amdgcn_cvt_pkrtz(a, b));
}
__device__ __forceinline__ void gl_lds(const void* g, void* l) {
    __builtin_amdgcn_global_load_lds((gvoid*)g, (lvoid*)l, 16, 0, 0);
}

// ---------------- kernel 1: W fp16 B-frag blobs. Wf[ks_g][lane][8], ks_g = src*32+hemb*4+ks.
// q-rows of W scaled by sqrt(128) (compensates QK_SCALE baked into staged q).
__global__ __launch_bounds__(256) void ktransW(const float* __restrict__ igk,
                                               const float* __restrict__ fgk,
                                               ushort_t* __restrict__ Wf) {
    int gid = blockIdx.x * 256 + threadIdx.x;  // 0..6143
    int ks_g = gid >> 6, lane = gid & 63;
    int n = lane & 15, lg = lane >> 4;
    int src = ks_g >> 5, rem = ks_g & 31;
    int hemb = rem >> 2, ks = rem & 3;
    int e0 = src * 1024 + hemb * 128 + ks * 32 + lg * 8;
    float scale = (src == 0) ? RS128 : 1.0f;
    const float* col = (n < 8) ? igk : fgk;
    int nn = n & 7;
    union { ushort_t u[8]; uint4 v4; } P;
    #pragma unroll
    for (int e = 0; e < 8; ++e) P.u[e] = f2h(col[(size_t)(e0 + e) * 8 + nn] * scale);
    *(uint4*)((char*)Wf + ks_g * 1024 + lane * 16) = P.v4;
}

// ---------------- kernel 2: fused split + gate GEMM. Block = (b, 16-row strip), 256 blocks.
// Loads q,k,v rows once; writes pre-swizzled Q/K fp16 tiles, Vt in [tile][joct][128d][8j]
// layout (coalesced B-frag reads later), and computes gate preacts via MFMA from LDS.
__global__ __launch_bounds__(256) void kprep(const float* __restrict__ q,
                                             const float* __restrict__ k,
                                             const float* __restrict__ v,
                                             const ushort_t* __restrict__ Wf,
                                             const float* __restrict__ igb,
                                             const float* __restrict__ fgb,
                                             ushort_t* __restrict__ Qf,
                                             ushort_t* __restrict__ Kf,
                                             ushort_t* __restrict__ Vt,
                                             float* __restrict__ igp_t,
                                             float* __restrict__ fgp_t) {
    __shared__ __align__(16) ushort_t xs[3 * 8 * 16 * 128];  // 96KB [src*8+h][16r][128c] swz
    __shared__ __align__(16) float red[4][64][4];
    const int blk = blockIdx.x;
    const int b = blk >> 7, strip = blk & 127;
    const int s0 = strip * 16;
    const int tile = strip >> 2, subrow = (strip & 3) * 16;
    const int t = threadIdx.x;
    const int w = t >> 6, lane = t & 63;
    const int ll = lane & 15, lg = lane >> 4;

    #pragma unroll
    for (int src = 0; src < 3; ++src) {
        const float* sp = (src == 0 ? q : src == 1 ? k : v) + ((size_t)b * S_LEN + s0) * EMB_D;
        float scale = (src == 0) ? QK_SCALE : 1.0f;
        #pragma unroll
        for (int i = 0; i < 16; ++i) {
            int f = i * 256 + t;
            int r = f >> 8, c4 = f & 255;
            int col = c4 * 4;
            float4 x = *(const float4*)(sp + (size_t)r * EMB_D + col);
            ushort4 H;
            H.x = f2h(x.x * scale); H.y = f2h(x.y * scale);
            H.z = f2h(x.z * scale); H.w = f2h(x.w * scale);
            int hh = col >> 7, d0 = col & 127;
            *(ushort4*)((char*)xs + ((((src * 8 + hh) * 16 + r) * 256 + d0 * 2) ^ ((r & 7) << 4))) = H;
            if (src < 2) {
                char* dst = (char*)(src ? Kf : Qf) + ((size_t)(b * 8 + hh) * 32 + tile) * 16384;
                *(ushort4*)(dst + (((subrow + r) * 256 + d0 * 2) ^ ((r & 7) << 4))) = H;
            }
        }
    }
    __syncthreads();
    // Vt transpose from LDS: [bh][tile][joct][128 d][8 j]
    #pragma unroll
    for (int it = 0; it < 8; ++it) {
        int item = it * 256 + t;           // 0..2047
        int d = item & 127, jo = (item >> 7) & 1, hh = item >> 8;
        union { ushort_t u[8]; uint4 v4; } P;
        #pragma unroll
        for (int e = 0; e < 8; ++e) {
            int r = jo * 8 + e;
            P.u[e] = *(const ushort_t*)((const char*)xs
                       + ((((16 + hh) * 16 + r) * 256 + d * 2) ^ ((r & 7) << 4)));
        }
        char* vd = (char*)Vt + ((size_t)(b * 8 + hh) * 32 + tile) * 16384
                 + ((strip & 3) * 2 + jo) * 2048 + d * 16;
        *(uint4*)vd = P.v4;
    }
    // gate GEMM: wave w does 6 of 24 (src,hemb) rounds; 4-way partial reduce via LDS
    f32x4 acc = {0.f, 0.f, 0.f, 0.f};
    for (int ri = w * 6; ri < w * 6 + 6; ++ri) {
        int src = ri >> 3, hemb = ri & 7;
        #pragma unroll
        for (int ks = 0; ks < 4; ++ks) {
            f16x8 af = *(const f16x8*)((const char*)xs
                        + ((((src * 8 + hemb) * 16 + ll) * 256 + ks * 64 + lg * 16) ^ ((ll & 7) << 4)));
            f16x8 bf = *(const f16x8*)((const char*)Wf + (src * 32 + hemb * 4 + ks) * 1024 + lane * 16);
            acc = __builtin_amdgcn_mfma_f32_16x16x32_f16(af, bf, acc, 0, 0, 0);
        }
    }
    *(f32x4*)&red[w][lane][0] = acc;
    __syncthreads();
    if (w == 0) {
        f32x4 o2 = acc;
        #pragma unroll
        for (int ww = 1; ww < 4; ++ww) o2 += *(const f32x4*)&red[ww][lane][0];
        float bias = (ll < 8) ? igb[ll] : fgb[ll - 8];
        float* dst = (ll < 8) ? igp_t : fgp_t;
        size_t ob = (size_t)(b * 8 + (ll & 7)) * S_LEN + s0 + lg * 4;
        #pragma unroll
        for (int r = 0; r < 4; ++r) dst[ob + r] = o2[r] + bias;
    }
}

// ---------------- kernel 3: per-(b,h) prefix scans, single wave, no barriers.
__global__ __launch_bounds__(64) void kscan(const float* __restrict__ igp_t,
                                            const float* __restrict__ fgp_t,
                                            float* __restrict__ a_w,
                                            float* __restrict__ pm_w,
                                            float* __restrict__ nf_w) {
    const int bh = blockIdx.x;
    const int l = threadIdx.x;
    const int base = bh * S_LEN + l * 32;
    float lf[32];
    #pragma unroll
    for (int i = 0; i < 8; ++i) {
        float4 fg = *(const float4*)(fgp_t + base + i * 4);
        float* p = &lf[i * 4];
        p[0] = fminf(fg.x, 0.f) - log1pf(__expf(-fabsf(fg.x)));
        p[1] = fminf(fg.y, 0.f) - log1pf(__expf(-fabsf(fg.y)));
        p[2] = fminf(fg.z, 0.f) - log1pf(__expf(-fabsf(fg.z)));
        p[3] = fminf(fg.w, 0.f) - log1pf(__expf(-fabsf(fg.w)));
    }
    #pragma unroll
    for (int i = 1; i < 32; ++i) lf[i] += lf[i - 1];
    float tot = lf[31];
    #pragma unroll
    for (int d = 1; d < 64; d <<= 1) {
        float n = __shfl_up(tot, d, 64);
        if (l >= d) tot += n;
    }
    float excl = tot - lf[31];
    float cs[32], a[32];
    #pragma unroll
    for (int i = 0; i < 8; ++i) {
        float4 ig = *(const float4*)(igp_t + base + i * 4);
        float iv[4] = {ig.x, ig.y, ig.z, ig.w};
        #pragma unroll
        for (int e = 0; e < 4; ++e) {
            int idx = i * 4 + e;
            cs[idx] = excl + lf[idx];
            a[idx] = iv[e] - cs[idx];
            a_w[base + idx] = a[idx] * LOG2E;
        }
    }
    float am[32];
    am[0] = a[0];
    #pragma unroll
    for (int i = 1; i < 32; ++i) am[i] = fmaxf(am[i - 1], a[i]);
    float mtot = am[31];
    #pragma unroll
    for (int d = 1; d < 64; d <<= 1) {
        float n = __shfl_up(mtot, d, 64);
        if (l >= d) mtot = fmaxf(mtot, n);
    }
    float exm = __shfl_up(mtot, 1, 64);
    if (l == 0) exm = -INFINITY;
    #pragma unroll
    for (int i = 0; i < 32; ++i) {
        float pmv = fmaxf(exm, am[i]);
        pm_w[base + i] = pmv * LOG2E;
        nf_w[base + i] = __expf(-(cs[i] + pmv));
    }
}

// ---------------- kernel 4: main core. 256 blocks x 512 thr (2 groups x 4 waves).
// Block = (bh, pair): rt = pair then 31-pair (uniform 17 supersteps). Group g does
// ct = g, g+2,... K double-buffered in LDS (global_load_lds); V and a prefetched
// L2->REGISTERS one superstep ahead (coalesced via joct Vt layout); Cs via LDS.
// Mid-step barrier lgkm-only; vmcnt(0) only at superstep end (full-ss covered).
__global__ __launch_bounds__(512) void kmain(const ushort_t* __restrict__ Qf,
                                             const ushort_t* __restrict__ Kf,
                                             const ushort_t* __restrict__ Vt,
                                             const float* __restrict__ a_w,
                                             const float* __restrict__ pm_w,
                                             const float* __restrict__ nf_w,
                                             float* __restrict__ out) {
    __shared__ __align__(16) ushort_t Kbuf[2][2][8192];  // [group][dbuf] 64KB
    __shared__ __align__(16) ushort_t Csh[2][4096];      // [group] 16KB
    __shared__ float redL[2][2][64];

    const int blk = blockIdx.x;
    const int bh = blk & 15;             // XCD = blk%8 = bh&7 (matches kprep writes)
    const int pair = blk >> 4;           // 0..15
    const int b = bh >> 3, h = bh & 7;
    const int t = threadIdx.x;
    const int w = t >> 6, lane = t & 63;
    const int g = w >> 2, wl = w & 3;
    const int wr = wl >> 1, wc = wl & 1;
    const int lg = lane >> 4, ll = lane & 15;
    const int sw = (ll & 7) << 4;

    const char* q_b = (const char*)Qf + (size_t)bh * 524288;
    const char* k_b = (const char*)Kf + (size_t)bh * 524288;
    const char* v_b = (const char*)Vt + (size_t)bh * 524288;
    const float* aw = a_w + bh * S_LEN;

    float* accX = (float*)&Kbuf[0][0][0];   // 32KB combine region (post-loop alias)
    float* rsX  = (float*)&Csh[0][0];       // 2KB (post-loop alias)

    for (int half = 0; half < 2; ++half) {
        const int rt = half ? (31 - pair) : pair;
        const int row0 = rt * 64;
        const int nss = (rt >> 1) + 1;
        __syncthreads();   // previous half's LDS (incl combine aliases) done

        // Q frags direct from global pre-swizzled tile
        const char* qt = q_b + (size_t)rt * 16384;
        f16x8 qf[2][4];
        #pragma unroll
        for (int ib = 0; ib < 2; ++ib) {
            int row = 32 * wr + 16 * ib + ll;
            #pragma unroll
            for (int kk = 0; kk < 4; ++kk)
                qf[ib][kk] = *(const f16x8*)(qt + ((row * 256 + lg * 16 + kk * 64) ^ ((row & 7) << 4)));
        }
        float pm2[2];
        #pragma unroll
        for (int ib = 0; ib < 2; ++ib)
            pm2[ib] = pm_w[bh * S_LEN + row0 + 32 * wr + 16 * ib + ll];

        // stage K(g) into buf0; prefetch V(g), a(g) into regs
        f16x8 bvA[2][4], bvB[2][4];
        f32x4 avA[2] = {{0.f,0.f,0.f,0.f},{0.f,0.f,0.f,0.f}};
        f32x4 avB[2] = {{0.f,0.f,0.f,0.f},{0.f,0.f,0.f,0.f}};
        if (g <= rt) {
            const char* kt = k_b + (size_t)g * 16384;
            #pragma unroll
            for (int i = 0; i < 4; ++i) {
                int o = (wl * 4 + i) * 1024 + lane * 16;
                gl_lds(kt + o, (char*)&Kbuf[g][0][0] + o);
            }
            const char* vt = v_b + (size_t)g * 16384;
            #pragma unroll
            for (int kk = 0; kk < 2; ++kk)
                #pragma unroll
                for (int vf = 0; vf < 4; ++vf)
                    bvA[kk][vf] = *(const f16x8*)(vt + (kk * 4 + lg) * 2048 + (64 * wc + 16 * vf + ll) * 16);
            #pragma unroll
            for (int jb = 0; jb < 2; ++jb)
                avA[jb] = *(const f32x4*)(aw + g * 64 + 32 * wc + 16 * jb + 4 * lg);
        }
        asm volatile("s_waitcnt vmcnt(0)" ::: "memory");
        __builtin_amdgcn_s_barrier();

        f32x4 zero4 = {0.f, 0.f, 0.f, 0.f};
        f32x4 accO[2][4];
        #pragma unroll
        for (int ib = 0; ib < 2; ++ib)
            #pragma unroll
            for (int vf = 0; vf < 4; ++vf) accO[ib][vf] = zero4;
        float rs[2] = {0.f, 0.f};

        auto STEP = [&](int ssv, int P, f16x8 (&bvC)[2][4], f16x8 (&bvN)[2][4],
                        f32x4 (&avC)[2], f32x4 (&avN)[2]) {
            const int myct = 2 * ssv + g;
            const int nxct = myct + 2;
            if (nxct <= rt) {   // issue next staging (drains at END of this superstep)
                const char* kt = k_b + (size_t)nxct * 16384;
                #pragma unroll
                for (int i = 0; i < 4; ++i) {
                    int o = (wl * 4 + i) * 1024 + lane * 16;
                    gl_lds(kt + o, (char*)&Kbuf[g][P ^ 1][0] + o);
                }
                const char* vt = v_b + (size_t)nxct * 16384;
                #pragma unroll
                for (int kk = 0; kk < 2; ++kk)
                    #pragma unroll
                    for (int vf = 0; vf < 4; ++vf)
                        bvN[kk][vf] = *(const f16x8*)(vt + (kk * 4 + lg) * 2048 + (64 * wc + 16 * vf + ll) * 16);
                #pragma unroll
                for (int jb = 0; jb < 2; ++jb)
                    avN[jb] = *(const f32x4*)(aw + nxct * 64 + 32 * wc + 16 * jb + 4 * lg);
            }
            const bool act = (myct <= rt);
            if (act) {
                const char* kl = (const char*)&Kbuf[g][P][0];
                f32x4 accST[2][2];
                accST[0][0] = zero4; accST[0][1] = zero4;
                accST[1][0] = zero4; accST[1][1] = zero4;
                __builtin_amdgcn_s_setprio(1);
                #pragma unroll
                for (int kk = 0; kk < 4; ++kk) {
                    f16x8 kf0 = *(const f16x8*)(kl + (((32 * wc + ll) * 256 + lg * 16 + kk * 64) ^ sw));
                    f16x8 kf1 = *(const f16x8*)(kl + (((32 * wc + 16 + ll) * 256 + lg * 16 + kk * 64) ^ sw));
                    accST[0][0] = __builtin_amdgcn_mfma_f32_16x16x32_f16(kf0, qf[0][kk], accST[0][0], 0, 0, 0);
                    accST[0][1] = __builtin_amdgcn_mfma_f32_16x16x32_f16(kf0, qf[1][kk], accST[0][1], 0, 0, 0);
                    accST[1][0] = __builtin_amdgcn_mfma_f32_16x16x32_f16(kf1, qf[0][kk], accST[1][0], 0, 0, 0);
                    accST[1][1] = __builtin_amdgcn_mfma_f32_16x16x32_f16(kf1, qf[1][kk], accST[1][1], 0, 0, 0);
                }
                __builtin_amdgcn_s_setprio(0);
                const bool diag = (myct == rt);
                #pragma unroll
                for (int jb = 0; jb < 2; ++jb) {
                    #pragma unroll
                    for (int ib = 0; ib < 2; ++ib) {
                        int il = 32 * wr + 16 * ib + ll;
                        float cv[4];
                        #pragma unroll
                        for (int r = 0; r < 4; ++r) {
                            int jl = 32 * wc + 16 * jb + 4 * lg + r;
                            float x = accST[jb][ib][r] * exp2f(avC[jb][r] - pm2[ib]);
                            if (diag && jl > il) x = 0.f;
                            rs[ib] += x;
                            cv[r] = x;
                        }
                        int off = (il * 128 + (32 * wc + 16 * jb + 4 * lg) * 2) ^ ((il & 7) << 4);
                        uint2 pk2; pk2.x = pk2h(cv[0], cv[1]); pk2.y = pk2h(cv[2], cv[3]);
                        *(uint2*)((char*)&Csh[g][0] + off) = pk2;
                    }
                }
            }
            asm volatile("s_waitcnt lgkmcnt(0)" ::: "memory");
            __builtin_amdgcn_s_barrier();
            if (act) {
                __builtin_amdgcn_s_setprio(1);
                #pragma unroll
                for (int kk = 0; kk < 2; ++kk)
                    #pragma unroll
                    for (int ib = 0; ib < 2; ++ib) {
                        int rowA = 32 * wr + 16 * ib + ll;
                        f16x8 pa = *(const f16x8*)((const char*)&Csh[g][0]
                                                   + ((rowA * 128 + lg * 16 + kk * 64) ^ ((rowA & 7) << 4)));
                        #pragma unroll
                        for (int vf = 0; vf < 4; ++vf)
                            accO[ib][vf] = __builtin_amdgcn_mfma_f32_16x16x32_f16(pa, bvC[kk][vf], accO[ib][vf], 0, 0, 0);
                    }
                __builtin_amdgcn_s_setprio(0);
            }
            asm volatile("s_waitcnt vmcnt(0)" ::: "memory");
            __builtin_amdgcn_s_barrier();
        };

        for (int ss = 0; ss < nss; ss += 2) {
            STEP(ss, 0, bvA, bvB, avA, avB);
            if (ss + 1 < nss) STEP(ss + 1, 1, bvB, bvA, avB, avA);
        }

        // ---- combine the two groups' partials, then finalize (group0)
        __syncthreads();
        const int li = wl * 64 + lane;
        if (g == 1) {
            #pragma unroll
            for (int ib = 0; ib < 2; ++ib)
                #pragma unroll
                for (int vf = 0; vf < 4; ++vf)
                    *(f32x4*)&accX[li * 32 + (ib * 4 + vf) * 4] = accO[ib][vf];
            rsX[li * 2 + 0] = rs[0];
            rsX[li * 2 + 1] = rs[1];
        }
        __syncthreads();
        if (g == 0) {
            #pragma unroll
            for (int ib = 0; ib < 2; ++ib)
                #pragma unroll
                for (int vf = 0; vf < 4; ++vf)
                    accO[ib][vf] += *(const f32x4*)&accX[li * 32 + (ib * 4 + vf) * 4];
            rs[0] += rsX[li * 2 + 0];
            rs[1] += rsX[li * 2 + 1];
            #pragma unroll
            for (int ib = 0; ib < 2; ++ib) {
                rs[ib] += __shfl_xor(rs[ib], 16);
                rs[ib] += __shfl_xor(rs[ib], 32);
            }
            if (lg == 0) {
                redL[0][wc][32 * wr + ll] = rs[0];
                redL[0][wc][32 * wr + 16 + ll] = rs[1];
            }
        }
        __syncthreads();
        if (g == 0) {
            float invn[2][4];
            #pragma unroll
            for (int ib = 0; ib < 2; ++ib)
                #pragma unroll
                for (int r = 0; r < 4; ++r) {
                    int il = 32 * wr + 16 * ib + 4 * lg + r;
                    float tot = redL[0][0][il] + redL[0][1][il];
                    float nf = nf_w[bh * S_LEN + row0 + il];
                    invn[ib][r] = 1.0f / (fmaxf(fabsf(tot), nf) + 1e-6f);
                }
            float ssq[2][4] = {{0.f, 0.f, 0.f, 0.f}, {0.f, 0.f, 0.f, 0.f}};
            #pragma unroll
            for (int ib = 0; ib < 2; ++ib)
                #pragma unroll
                for (int vf = 0; vf < 4; ++vf)
                    #pragma unroll
                    for (int r = 0; r < 4; ++r) {
                        float hv = accO[ib][vf][r] * invn[ib][r];
                        ssq[ib][r] += hv * hv;
                    }
            #pragma unroll
            for (int m = 1; m < 16; m <<= 1)
                #pragma unroll
                for (int ib = 0; ib < 2; ++ib)
                    #pragma unroll
                    for (int r = 0; r < 4; ++r) ssq[ib][r] += __shfl_xor(ssq[ib][r], m);
            if (ll == 0) {
                #pragma unroll
                for (int ib = 0; ib < 2; ++ib)
                    #pragma unroll
                    for (int r = 0; r < 4; ++r)
                        redL[1][wc][32 * wr + 16 * ib + 4 * lg + r] = ssq[ib][r];
            }
            __builtin_amdgcn_s_barrier();
            float* ob = out + ((size_t)b * S_LEN + row0) * EMB_D + h * 128;
            #pragma unroll
            for (int ib = 0; ib < 2; ++ib)
                #pragma unroll
                for (int r = 0; r < 4; ++r) {
                    int il = 32 * wr + 16 * ib + 4 * lg + r;
                    float sst = redL[1][0][il] + redL[1][1][il];
                    float scl = rsqrtf(sst * (1.0f / 128.0f) + 1e-6f) * invn[ib][r];
                    #pragma unroll
                    for (int vf = 0; vf < 4; ++vf) {
                        int d = 64 * wc + 16 * vf + ll;
                        ob[(size_t)il * EMB_D + d] = accO[ib][vf][r] * scl;
                    }
                }
        } else {
            __builtin_amdgcn_s_barrier();   // match g0's barrier
        }
    }
}

extern "C" void kernel_launch(void* const* d_in, const int* in_sizes, int n_in,
                              void* d_out, int out_size, void* d_ws, size_t ws_size,
                              hipStream_t stream) {
    const float* q   = (const float*)d_in[0];
    const float* k   = (const float*)d_in[1];
    const float* v   = (const float*)d_in[2];
    const float* igk = (const float*)d_in[3];
    const float* igb = (const float*)d_in[4];
    const float* fgk = (const float*)d_in[5];
    const float* fgb = (const float*)d_in[6];
    float* out = (float*)d_out;

    char* W = (char*)d_ws;
    ushort_t* Wf   = (ushort_t*)(W);                 //  98304 B
    float* igp_t   = (float*)(W + 98304);            // 131072 B
    float* fgp_t   = (float*)(W + 229376);
    float* a_w     = (float*)(W + 360448);
    float* pm_w    = (float*)(W + 491520);
    float* nf_w    = (float*)(W + 622592);
    ushort_t* Qf   = (ushort_t*)(W + 753664);        // 8 MB each
    ushort_t* Kf   = (ushort_t*)(W + 753664 + 1 * 8388608ull);
    ushort_t* Vt   = (ushort_t*)(W + 753664 + 2 * 8388608ull);  // total ~25.9 MB

    ktransW<<<24, 256, 0, stream>>>(igk, fgk, Wf);
    kprep<<<256, 256, 0, stream>>>(q, k, v, Wf, igb, fgb, Qf, Kf, Vt, igp_t, fgp_t);
    kscan<<<16, 64, 0, stream>>>(igp_t, fgp_t, a_w, pm_w, nf_w);
    kmain<<<256, 512, 0, stream>>>(Qf, Kf, Vt, a_w, pm_w, nf_w, out);
}